// Round 7
// baseline (1047.607 us; speedup 1.0000x reference)
//
#include <hip/hip_runtime.h>
#include <stdint.h>

typedef unsigned short u16;
typedef __bf16 bf16x8 __attribute__((ext_vector_type(8)));
typedef float f32x4 __attribute__((ext_vector_type(4)));

#define DEVI __device__ __forceinline__

static constexpr int DIM = 768;
static constexpr int SEQL = 3136;   // 56*56
static constexpr int MROWS = 25088; // 8*3136
static constexpr int HEADS = 12;
static constexpr int HD = 64;
static constexpr int NW = 196;      // tokens per window
static constexpr float QSCALE = 0.125f; // 64^-0.5
// attn LDS: sK [208][64]u16 26624 + sP 4*[16][232]u16 29696 + sT 4*[16][64]f32 16384
static constexpr int ATTN_SMEM = 72704;
static constexpr int GEMM_SMEM = 131072; // 2 K-tile bufs x (A 32KB + B 32KB)

DEVI float b2f(u16 u) { union { unsigned i; float f; } v; v.i = ((unsigned)u) << 16; return v.f; }
DEVI u16 f2b(float f) { union { float f; unsigned u; } v; v.f = f; return (u16)((v.u + 0x7FFFu + ((v.u >> 16) & 1u)) >> 16); }

DEVI void gl_lds16(const void* g, void* l) {
  __builtin_amdgcn_global_load_lds((const __attribute__((address_space(1))) void*)g,
                                   (__attribute__((address_space(3))) void*)l, 16, 0, 0);
}

// 8B-aligned global bf16x8 load (two dwordx2)
DEVI bf16x8 ldg_b8(const u16* p) {
  union { uint4 u; bf16x8 v; } r;
  const uint2* p2 = (const uint2*)p;
  uint2 lo = p2[0], hi = p2[1];
  r.u.x = lo.x; r.u.y = lo.y; r.u.z = hi.x; r.u.w = hi.y;
  return r.v;
}

// ---------------- weight transpose + f32->bf16 convert: W[K][N] -> Wt[N][K] ---------------
__global__ __launch_bounds__(256) void transpose_cvt(const float* __restrict__ in,
                                                     u16* __restrict__ out, int K, int N) {
  __shared__ float t[32][33];
  int n0 = blockIdx.x * 32, k0 = blockIdx.y * 32;
  int tx = threadIdx.x, ty = threadIdx.y; // (32,8)
  #pragma unroll
  for (int i = ty; i < 32; i += 8) t[i][tx] = in[(size_t)(k0 + i) * N + n0 + tx];
  __syncthreads();
  #pragma unroll
  for (int i = ty; i < 32; i += 8) out[(size_t)(n0 + i) * K + k0 + tx] = f2b(t[tx][i]);
}

// ---------------- rel-pos tables f32 [27][64] -> bf16 [2][32][64] (rows>=27 zero) --------
__global__ __launch_bounds__(256) void cvt_rpb(const float* __restrict__ rph,
                                               const float* __restrict__ rpw,
                                               u16* __restrict__ rpb) {
  int i = blockIdx.x * 256 + threadIdx.x;  // 0..4095
  int tbl = i >> 11, r = (i >> 6) & 31, c = i & 63;
  float v = (r < 27) ? (tbl ? rpw : rph)[r * 64 + c] : 0.f;
  rpb[i] = f2b(v);
}

// ---------------- layernorm (768 cols); REMAP=window-partition the output row ---------------
template<bool REMAP>
__global__ __launch_bounds__(256) void ln_kernel(const float* __restrict__ xin,
                                                 const float* __restrict__ g,
                                                 const float* __restrict__ bb,
                                                 u16* __restrict__ outw) {
  __shared__ float red[8];
  const int r = blockIdx.x;
  const int tid = threadIdx.x;
  const float* xr = xin + (size_t)r * DIM;
  float v0 = xr[tid], v1 = xr[tid + 256], v2 = xr[tid + 512];
  float s1 = v0 + v1 + v2;
  float s2 = v0 * v0 + v1 * v1 + v2 * v2;
  #pragma unroll
  for (int o = 32; o > 0; o >>= 1) { s1 += __shfl_down(s1, o); s2 += __shfl_down(s2, o); }
  const int l = tid & 63, w = tid >> 6;
  if (l == 0) { red[w] = s1; red[w + 4] = s2; }
  __syncthreads();
  float ts = red[0] + red[1] + red[2] + red[3];
  float tss = red[4] + red[5] + red[6] + red[7];
  float mean = ts * (1.f / 768.f);
  float var = tss * (1.f / 768.f) - mean * mean;
  float rstd = rsqrtf(var + 1e-5f);
  size_t orow;
  if constexpr (REMAP) {
    int b = r / SEQL, s = r % SEQL;
    int h = s / 56, ww = s % 56;
    orow = (size_t)(b * 16 + (h / 14) * 4 + (ww / 14)) * NW + (h % 14) * 14 + (ww % 14);
  } else {
    orow = (size_t)r;
  }
  u16* orp = outw + orow * DIM;
  orp[tid]       = f2b((v0 - mean) * rstd * g[tid]       + bb[tid]);
  orp[tid + 256] = f2b((v1 - mean) * rstd * g[tid + 256] + bb[tid + 256]);
  orp[tid + 512] = f2b((v2 - mean) * rstd * g[tid + 512] + bb[tid + 512]);
}

// ---------------- GEMM v3: 256x256, BK=64, 8 waves, 8-phase counted-vmcnt schedule --------
struct Epi {
  const float* bias;
  const float* x;   // proj: residual input (f32)
  float* outf;      // proj/fc2: f32 out (d_out)
  u16* q; u16* k; u16* v; // qkv outputs (v transposed: [wh][64][196])
  u16* o16;         // fc1 out
};

#define MFMA_BF16 __builtin_amdgcn_mfma_f32_16x16x32_bf16

template<int K, int N, int EPI>
__global__ __launch_bounds__(512, 2)
void gemm3_ep(const u16* __restrict__ A, const u16* __restrict__ Bt, Epi ep) {
  extern __shared__ __align__(16) char gsm[];
  u16* const sA0 = (u16*)gsm;              // even K-tiles, A [256][64]
  u16* const sA1 = (u16*)(gsm + 32768);    // odd  K-tiles, A
  u16* const sB0 = (u16*)(gsm + 65536);    // even K-tiles, B
  u16* const sB1 = (u16*)(gsm + 98304);    // odd  K-tiles, B

  constexpr int NBN = N / 256;
  constexpr int NKT = K / 64;              // even (12 or 48)
  constexpr int NIT = NKT / 2;

  const int tid = threadIdx.x;
  const int l = tid & 63, w = tid >> 6;
  const int lr = l & 15, lg = l >> 4;

  // bijective XCD swizzle (m204)
  const int nwg = gridDim.x;
  const int orig = blockIdx.x;
  const int qq = nwg >> 3, rr = nwg & 7;
  const int xcd = orig & 7, bidx = orig >> 3;
  const int wg = (xcd < rr ? xcd * (qq + 1) : rr * (qq + 1) + (xcd - rr) * qq) + bidx;
  const int bm = wg / NBN, bn = wg % NBN;
  const int wm = (w >> 2) * 128, wn = (w & 3) * 64;  // wave tile 128x64

  const u16* Ab = A + (size_t)bm * 256 * K;
  const u16* Bb = Bt + (size_t)bn * 256 * K;

  // staging: pass p covers rows [64p,64p+64), thread row = p*64+w*8+(l>>3), phys 16B-slot l&7
  // holds logical slot (l&7)^(row&7): pre-swizzled source col, linear LDS dest (rule #21).
  int asrc[4];
  #pragma unroll
  for (int p = 0; p < 4; ++p) {
    int row = p * 64 + w * 8 + (l >> 3);
    asrc[p] = row * K + (((l & 7) ^ (row & 7)) << 3);
  }

  // stage one half-tile (2 x gl_lds16). hid: 0=A rows 0-127, 1=A rows 128-255, 2=B half0, 3=B half1
  #define STG(kt, hid, dA, dB) do {                                          \
    const u16* _s = ((hid) < 2) ? Ab : Bb;                                   \
    u16* _d = ((hid) < 2) ? (dA) : (dB);                                     \
    _Pragma("unroll")                                                        \
    for (int _p = 0; _p < 2; ++_p) {                                         \
      int _pp = ((hid) & 1) * 2 + _p;                                        \
      gl_lds16(_s + asrc[_pp] + (size_t)(kt) * 64, (char*)_d + _pp * 8192 + tid * 16); \
    } } while (0)

  const int p0 = lg ^ (lr & 7);   // phys slot for kk=0
  const int p1 = p0 ^ 4;          // phys slot for kk=1

  f32x4 zero4 = {0.f, 0.f, 0.f, 0.f};
  f32x4 acc[8][4];
  #pragma unroll
  for (int i = 0; i < 8; ++i)
    #pragma unroll
    for (int j = 0; j < 4; ++j) acc[i][j] = zero4;

  // ---- prologue: tile0 full, tile1 B-halves; wait tile0 (4 newest outstanding allowed)
  STG(0, 0, sA0, sB0); STG(0, 1, sA0, sB0); STG(0, 2, sA0, sB0); STG(0, 3, sA0, sB0);
  STG(1, 2, sA1, sB1); STG(1, 3, sA1, sB1);
  asm volatile("s_waitcnt vmcnt(4)" ::: "memory");
  __builtin_amdgcn_s_barrier();

  bf16x8 afr[4][2], bfr[4][2];

  for (int i = 0; i < NIT; ++i) {
    const int te = 2 * i, to = te + 1;
    const bool nl = (i + 1 < NIT);     // not last iteration

    // ===== P1: read E A(mf0-3) + B(nf0-1); stage A0(to) -> odd buf
    #pragma unroll
    for (int mf = 0; mf < 4; ++mf) {
      afr[mf][0] = *(const bf16x8*)(sA0 + (wm + mf * 16 + lr) * 64 + p0 * 8);
      afr[mf][1] = *(const bf16x8*)(sA0 + (wm + mf * 16 + lr) * 64 + p1 * 8);
    }
    #pragma unroll
    for (int nf = 0; nf < 2; ++nf) {
      bfr[nf][0] = *(const bf16x8*)(sB0 + (wn + nf * 16 + lr) * 64 + p0 * 8);
      bfr[nf][1] = *(const bf16x8*)(sB0 + (wn + nf * 16 + lr) * 64 + p1 * 8);
    }
    STG(to, 0, sA1, sB1);
    __builtin_amdgcn_s_barrier();
    asm volatile("s_waitcnt lgkmcnt(0)" ::: "memory");
    __builtin_amdgcn_s_setprio(1);
    #pragma unroll
    for (int mf = 0; mf < 4; ++mf)
      #pragma unroll
      for (int nf = 0; nf < 2; ++nf) {
        acc[mf][nf] = MFMA_BF16(afr[mf][0], bfr[nf][0], acc[mf][nf], 0, 0, 0);
        acc[mf][nf] = MFMA_BF16(afr[mf][1], bfr[nf][1], acc[mf][nf], 0, 0, 0);
      }
    __builtin_amdgcn_s_setprio(0);
    __builtin_amdgcn_s_barrier();

    // ===== P2: read E B(nf2-3); stage A1(to); MFMA mf0-3 x nf2-3
    #pragma unroll
    for (int nf = 2; nf < 4; ++nf) {
      bfr[nf][0] = *(const bf16x8*)(sB0 + (wn + nf * 16 + lr) * 64 + p0 * 8);
      bfr[nf][1] = *(const bf16x8*)(sB0 + (wn + nf * 16 + lr) * 64 + p1 * 8);
    }
    STG(to, 1, sA1, sB1);
    __builtin_amdgcn_s_barrier();
    asm volatile("s_waitcnt lgkmcnt(0)" ::: "memory");
    __builtin_amdgcn_s_setprio(1);
    #pragma unroll
    for (int mf = 0; mf < 4; ++mf)
      #pragma unroll
      for (int nf = 2; nf < 4; ++nf) {
        acc[mf][nf] = MFMA_BF16(afr[mf][0], bfr[nf][0], acc[mf][nf], 0, 0, 0);
        acc[mf][nf] = MFMA_BF16(afr[mf][1], bfr[nf][1], acc[mf][nf], 0, 0, 0);
      }
    __builtin_amdgcn_s_setprio(0);
    __builtin_amdgcn_s_barrier();

    // ===== P3: read E A(mf4-7); stage B0(te+2); MFMA mf4-7 x nf2-3
    #pragma unroll
    for (int mf = 0; mf < 4; ++mf) {
      afr[mf][0] = *(const bf16x8*)(sA0 + (wm + 64 + mf * 16 + lr) * 64 + p0 * 8);
      afr[mf][1] = *(const bf16x8*)(sA0 + (wm + 64 + mf * 16 + lr) * 64 + p1 * 8);
    }
    if (nl) STG(te + 2, 2, sA0, sB0);
    __builtin_amdgcn_s_barrier();
    asm volatile("s_waitcnt lgkmcnt(0)" ::: "memory");
    __builtin_amdgcn_s_setprio(1);
    #pragma unroll
    for (int mf = 0; mf < 4; ++mf)
      #pragma unroll
      for (int nf = 2; nf < 4; ++nf) {
        acc[4 + mf][nf] = MFMA_BF16(afr[mf][0], bfr[nf][0], acc[4 + mf][nf], 0, 0, 0);
        acc[4 + mf][nf] = MFMA_BF16(afr[mf][1], bfr[nf][1], acc[4 + mf][nf], 0, 0, 0);
      }
    __builtin_amdgcn_s_setprio(0);
    __builtin_amdgcn_s_barrier();

    // ===== P4: stage B1(te+2); vmcnt (odd tile ready after barrier); MFMA mf4-7 x nf0-1
    if (nl) {
      STG(te + 2, 3, sA0, sB0);
      asm volatile("s_waitcnt vmcnt(4)" ::: "memory");
    } else {
      asm volatile("s_waitcnt vmcnt(0)" ::: "memory");
    }
    __builtin_amdgcn_s_barrier();
    __builtin_amdgcn_s_setprio(1);
    #pragma unroll
    for (int mf = 0; mf < 4; ++mf)
      #pragma unroll
      for (int nf = 0; nf < 2; ++nf) {
        acc[4 + mf][nf] = MFMA_BF16(afr[mf][0], bfr[nf][0], acc[4 + mf][nf], 0, 0, 0);
        acc[4 + mf][nf] = MFMA_BF16(afr[mf][1], bfr[nf][1], acc[4 + mf][nf], 0, 0, 0);
      }
    __builtin_amdgcn_s_setprio(0);
    __builtin_amdgcn_s_barrier();

    // ===== P5: read O A(mf0-3) + B(nf0-1); stage A0(te+2); MFMA mf0-3 x nf0-1
    #pragma unroll
    for (int mf = 0; mf < 4; ++mf) {
      afr[mf][0] = *(const bf16x8*)(sA1 + (wm + mf * 16 + lr) * 64 + p0 * 8);
      afr[mf][1] = *(const bf16x8*)(sA1 + (wm + mf * 16 + lr) * 64 + p1 * 8);
    }
    #pragma unroll
    for (int nf = 0; nf < 2; ++nf) {
      bfr[nf][0] = *(const bf16x8*)(sB1 + (wn + nf * 16 + lr) * 64 + p0 * 8);
      bfr[nf][1] = *(const bf16x8*)(sB1 + (wn + nf * 16 + lr) * 64 + p1 * 8);
    }
    if (nl) STG(te + 2, 0, sA0, sB0);
    __builtin_amdgcn_s_barrier();
    asm volatile("s_waitcnt lgkmcnt(0)" ::: "memory");
    __builtin_amdgcn_s_setprio(1);
    #pragma unroll
    for (int mf = 0; mf < 4; ++mf)
      #pragma unroll
      for (int nf = 0; nf < 2; ++nf) {
        acc[mf][nf] = MFMA_BF16(afr[mf][0], bfr[nf][0], acc[mf][nf], 0, 0, 0);
        acc[mf][nf] = MFMA_BF16(afr[mf][1], bfr[nf][1], acc[mf][nf], 0, 0, 0);
      }
    __builtin_amdgcn_s_setprio(0);
    __builtin_amdgcn_s_barrier();

    // ===== P6: read O B(nf2-3); stage A1(te+2); MFMA mf0-3 x nf2-3
    #pragma unroll
    for (int nf = 2; nf < 4; ++nf) {
      bfr[nf][0] = *(const bf16x8*)(sB1 + (wn + nf * 16 + lr) * 64 + p0 * 8);
      bfr[nf][1] = *(const bf16x8*)(sB1 + (wn + nf * 16 + lr) * 64 + p1 * 8);
    }
    if (nl) STG(te + 2, 1, sA0, sB0);
    __builtin_amdgcn_s_barrier();
    asm volatile("s_waitcnt lgkmcnt(0)" ::: "memory");
    __builtin_amdgcn_s_setprio(1);
    #pragma unroll
    for (int mf = 0; mf < 4; ++mf)
      #pragma unroll
      for (int nf = 2; nf < 4; ++nf) {
        acc[mf][nf] = MFMA_BF16(afr[mf][0], bfr[nf][0], acc[mf][nf], 0, 0, 0);
        acc[mf][nf] = MFMA_BF16(afr[mf][1], bfr[nf][1], acc[mf][nf], 0, 0, 0);
      }
    __builtin_amdgcn_s_setprio(0);
    __builtin_amdgcn_s_barrier();

    // ===== P7: read O A(mf4-7); stage B0(to+2); MFMA mf4-7 x nf2-3
    #pragma unroll
    for (int mf = 0; mf < 4; ++mf) {
      afr[mf][0] = *(const bf16x8*)(sA1 + (wm + 64 + mf * 16 + lr) * 64 + p0 * 8);
      afr[mf][1] = *(const bf16x8*)(sA1 + (wm + 64 + mf * 16 + lr) * 64 + p1 * 8);
    }
    if (nl) STG(to + 2, 2, sA1, sB1);
    __builtin_amdgcn_s_barrier();
    asm volatile("s_waitcnt lgkmcnt(0)" ::: "memory");
    __builtin_amdgcn_s_setprio(1);
    #pragma unroll
    for (int mf = 0; mf < 4; ++mf)
      #pragma unroll
      for (int nf = 2; nf < 4; ++nf) {
        acc[4 + mf][nf] = MFMA_BF16(afr[mf][0], bfr[nf][0], acc[4 + mf][nf], 0, 0, 0);
        acc[4 + mf][nf] = MFMA_BF16(afr[mf][1], bfr[nf][1], acc[4 + mf][nf], 0, 0, 0);
      }
    __builtin_amdgcn_s_setprio(0);
    __builtin_amdgcn_s_barrier();

    // ===== P8: stage B1(to+2); vmcnt(4) (even tile ready for next iter); MFMA mf4-7 x nf0-1
    if (nl) {
      STG(to + 2, 3, sA1, sB1);
      asm volatile("s_waitcnt vmcnt(4)" ::: "memory");
    }
    __builtin_amdgcn_s_barrier();
    __builtin_amdgcn_s_setprio(1);
    #pragma unroll
    for (int mf = 0; mf < 4; ++mf)
      #pragma unroll
      for (int nf = 0; nf < 2; ++nf) {
        acc[4 + mf][nf] = MFMA_BF16(afr[mf][0], bfr[nf][0], acc[4 + mf][nf], 0, 0, 0);
        acc[4 + mf][nf] = MFMA_BF16(afr[mf][1], bfr[nf][1], acc[4 + mf][nf], 0, 0, 0);
      }
    __builtin_amdgcn_s_setprio(0);
    __builtin_amdgcn_s_barrier();
  }
  #undef STG

  // ---- epilogue (wave tile 128x64 at (wm,wn)) ----
  const int mrow0 = bm * 256 + wm + lg * 4;
  const int ncol0 = bn * 256 + wn + lr;
  #pragma unroll
  for (int mf = 0; mf < 8; ++mf) {
    #pragma unroll
    for (int nf = 0; nf < 4; ++nf) {
      #pragma unroll
      for (int e = 0; e < 4; ++e) {
        int r = mrow0 + mf * 16 + e;
        int c = ncol0 + nf * 16;
        float v = acc[mf][nf][e] + ep.bias[c];
        if constexpr (EPI == 0) { // qkv scatter; v goes out transposed [wh][d][pos]
          int which = c / DIM;
          int hdc = c - which * DIM;
          int head = hdc >> 6, d = hdc & 63;
          int win = r / NW, pos = r - win * NW;
          size_t wh = (size_t)win * HEADS + head;
          if (which == 0)      ep.q[(wh * NW + pos) * HD + d] = f2b(v * QSCALE);
          else if (which == 1) ep.k[(wh * NW + pos) * HD + d] = f2b(v);
          else                 ep.v[(wh * HD + d) * NW + pos] = f2b(v);
        } else if constexpr (EPI == 1) { // proj: window-reverse + residual -> f32 d_out
          int win = r / NW, pos = r - win * NW;
          int b = win >> 4, wi = win & 15;
          int hh = (wi >> 2) * 14 + pos / 14;
          int ww = (wi & 3) * 14 + pos % 14;
          size_t orow = (size_t)b * SEQL + hh * 56 + ww;
          ep.outf[orow * DIM + c] = ep.x[orow * DIM + c] + v;
        } else if constexpr (EPI == 2) { // fc1: exact GELU -> bf16
          float gg = 0.5f * v * (1.f + erff(v * 0.70710678118654752f));
          ep.o16[(size_t)r * N + c] = f2b(gg);
        } else { // fc2: residual with d_out (x1), write f32
          size_t idxo = (size_t)r * N + c;
          ep.outf[idxo] = ep.outf[idxo] + v;
        }
      }
    }
  }
}

// ---------------- fused window attention v3: one 4-wave block per (win*head) ------------
__global__ __launch_bounds__(256, 2)
void attn_kernel(const u16* __restrict__ qbuf, const u16* __restrict__ kbuf,
                 const u16* __restrict__ vt, const u16* __restrict__ rpb,
                 u16* __restrict__ abuf) {
  extern __shared__ __align__(16) char smem[];
  u16* sK = (u16*)smem;                  // [208][64], 16B-slot s -> s^(row&7)
  u16* sP = (u16*)(smem + 26624);        // 4 x [16][232]
  float* sT = (float*)(smem + 56320);    // 4 x [16][64]: cols 0..26 h-term, 32..58 w-term

  const int tid = threadIdx.x;
  const int l = tid & 63, w = tid >> 6;
  const int lr = l & 15, lg = l >> 4;
  const int wh = blockIdx.x;             // win*12 + head
  const int win = wh / HEADS, head = wh - win * HEADS;

  const u16* Qg = qbuf + (size_t)wh * (NW * HD);
  const u16* Kg = kbuf + (size_t)wh * (NW * HD);
  const u16* Vg = vt + (size_t)wh * (HD * NW);   // [64][196]

  for (int t = tid; t < 1664; t += 256) {
    int r8 = t >> 3, c8 = t & 7;
    int s = (t & ~7) | (c8 ^ (r8 & 7));
    if (s >= 1568) s &= 1023;
    gl_lds16(Kg + s * 8, (char*)sK + t * 16);
  }
  __syncthreads();

  f32x4 zero4 = {0.f, 0.f, 0.f, 0.f};
  u16* myP = sP + w * (16 * 232);
  float* myT = sT + w * (16 * 64);

  for (int c = 0; c < 4; ++c) {
    const int chunk = w + 4 * c;
    if (chunk > 12) break;

    int qrow = chunk * 16 + lr; if (qrow > 195) qrow = 195;
    bf16x8 aq0 = *(const bf16x8*)(Qg + (size_t)qrow * HD + lg * 8);
    bf16x8 aq1 = *(const bf16x8*)(Qg + (size_t)qrow * HD + 32 + lg * 8);

    f32x4 th[2], tw[2];
    #pragma unroll
    for (int nf2 = 0; nf2 < 2; ++nf2) {
      const u16* bh = rpb + (nf2 * 16 + lr) * 64;
      const u16* bw = rpb + 2048 + (nf2 * 16 + lr) * 64;
      f32x4 a = zero4, b = zero4;
      a = MFMA_BF16(aq0, *(const bf16x8*)(bh + lg * 8), a, 0, 0, 0);
      a = MFMA_BF16(aq1, *(const bf16x8*)(bh + 32 + lg * 8), a, 0, 0, 0);
      b = MFMA_BF16(aq0, *(const bf16x8*)(bw + lg * 8), b, 0, 0, 0);
      b = MFMA_BF16(aq1, *(const bf16x8*)(bw + 32 + lg * 8), b, 0, 0, 0);
      th[nf2] = a; tw[nf2] = b;
    }
    #pragma unroll
    for (int nf2 = 0; nf2 < 2; ++nf2)
      #pragma unroll
      for (int e = 0; e < 4; ++e) {
        myT[(lg * 4 + e) * 64 + nf2 * 16 + lr]      = th[nf2][e];
        myT[(lg * 4 + e) * 64 + 32 + nf2 * 16 + lr] = tw[nf2][e];
      }

    f32x4 accs[13];
    #pragma unroll
    for (int nf = 0; nf < 13; ++nf) {
      int krow = nf * 16 + lr;
      int ksw = (krow & 7) << 3;
      bf16x8 b0 = *(const bf16x8*)(sK + krow * 64 + ((lg * 8) ^ ksw));
      bf16x8 b1 = *(const bf16x8*)(sK + krow * 64 + ((32 + lg * 8) ^ ksw));
      f32x4 cc = zero4;
      cc = MFMA_BF16(aq0, b0, cc, 0, 0, 0);
      cc = MFMA_BF16(aq1, b1, cc, 0, 0, 0);
      accs[nf] = cc;
    }

    int ihv[4], iwv[4];
    #pragma unroll
    for (int e = 0; e < 4; ++e) {
      int gi = chunk * 16 + lg * 4 + e;
      ihv[e] = (gi * 9363) >> 17;
      iwv[e] = gi - ihv[e] * 14;
    }
    float mrow[4] = {-3e38f, -3e38f, -3e38f, -3e38f};
    #pragma unroll
    for (int nf = 0; nf < 13; ++nf) {
      int j = nf * 16 + lr;
      int jh = (j * 9363) >> 17;
      int jw = j - jh * 14;
      #pragma unroll
      for (int e = 0; e < 4; ++e) {
        int ic = lg * 4 + e;
        float s = accs[nf][e]
                + myT[ic * 64 + ((ihv[e] - jh + 13) & 63)]
                + myT[ic * 64 + 32 + (iwv[e] - jw + 13)];
        if (nf == 12 && lr >= 4) s = -1e30f;
        accs[nf][e] = s;
        mrow[e] = fmaxf(mrow[e], s);
      }
    }
    #pragma unroll
    for (int e = 0; e < 4; ++e) {
      float v = mrow[e];
      v = fmaxf(v, __shfl_xor(v, 1)); v = fmaxf(v, __shfl_xor(v, 2));
      v = fmaxf(v, __shfl_xor(v, 4)); v = fmaxf(v, __shfl_xor(v, 8));
      mrow[e] = v;
    }
    float ssum[4] = {0.f, 0.f, 0.f, 0.f};
    #pragma unroll
    for (int nf = 0; nf < 13; ++nf)
      #pragma unroll
      for (int e = 0; e < 4; ++e) {
        float p = __expf(accs[nf][e] - mrow[e]);
        accs[nf][e] = p;
        ssum[e] += p;
      }
    #pragma unroll
    for (int e = 0; e < 4; ++e) {
      float v = ssum[e];
      v += __shfl_xor(v, 1); v += __shfl_xor(v, 2);
      v += __shfl_xor(v, 4); v += __shfl_xor(v, 8);
      ssum[e] = 1.f / v;
    }
    #pragma unroll
    for (int nf = 0; nf < 13; ++nf)
      #pragma unroll
      for (int e = 0; e < 4; ++e)
        myP[(lg * 4 + e) * 232 + nf * 16 + lr] = f2b(accs[nf][e] * ssum[e]);
    #pragma unroll
    for (int e = 0; e < 4; ++e)
      myP[(lg * 4 + e) * 232 + 208 + lr] = 0;

    f32x4 acco[4];
    #pragma unroll
    for (int nf = 0; nf < 4; ++nf) acco[nf] = zero4;
    #pragma unroll
    for (int ks = 0; ks < 7; ++ks) {
      bf16x8 ap = *(const bf16x8*)(myP + lr * 232 + ks * 32 + lg * 8);
      #pragma unroll
      for (int nf = 0; nf < 4; ++nf) {
        bf16x8 bv = ldg_b8(Vg + (size_t)(nf * 16 + lr) * NW + ks * 32 + lg * 8);
        acco[nf] = MFMA_BF16(ap, bv, acco[nf], 0, 0, 0);
      }
    }
    u16* ob = abuf + (size_t)win * NW * DIM + head * HD;
    #pragma unroll
    for (int nf = 0; nf < 4; ++nf)
      #pragma unroll
      for (int e = 0; e < 4; ++e) {
        int row = chunk * 16 + lg * 4 + e;
        if (row < 196) ob[(size_t)row * DIM + nf * 16 + lr] = f2b(acco[nf][e]);
      }
  }
}

// ---------------- host launch ---------------
extern "C" void kernel_launch(void* const* d_in, const int* in_sizes, int n_in,
                              void* d_out, int out_size, void* d_ws, size_t ws_size,
                              hipStream_t stream) {
  (void)in_sizes; (void)n_in; (void)out_size; (void)ws_size;
  const float* x    = (const float*)d_in[0];
  const float* ln1s = (const float*)d_in[1];
  const float* ln1b = (const float*)d_in[2];
  const float* qkvw = (const float*)d_in[3];
  const float* qkvb = (const float*)d_in[4];
  const float* rph  = (const float*)d_in[5];
  const float* rpw  = (const float*)d_in[6];
  const float* pjw  = (const float*)d_in[7];
  const float* pjb  = (const float*)d_in[8];
  const float* ln2s = (const float*)d_in[9];
  const float* ln2b = (const float*)d_in[10];
  const float* f1w  = (const float*)d_in[11];
  const float* f1b  = (const float*)d_in[12];
  const float* f2w  = (const float*)d_in[13];
  const float* f2b_ = (const float*)d_in[14];
  float* out = (float*)d_out;

  char* ws = (char*)d_ws;
  u16* qkvwT = (u16*)ws;              // [2304][768]
  u16* projwT = qkvwT + 1769472;      // [768][768]
  u16* fc1wT  = qkvwT + 2359296;      // [3072][768]
  u16* fc2wT  = qkvwT + 4718592;      // [768][3072]
  u16* xw   = (u16*)(ws + 14155776);  // [25088][768]
  u16* qbuf = (u16*)(ws + 52690944);  // [1536][196][64]
  u16* kbuf = qbuf + 19267584;
  u16* vtb  = kbuf + 19267584;        // [1536][64][196]
  u16* h2   = (u16*)(ws + 168296448); // [25088][768]
  u16* abuf = xw;                     // alias (xw dead after qkv gemm)
  u16* h1   = xw;                     // [25088][3072] spans xw+q+k+vT regions (all dead)
  u16* rpb  = h2;                     // [2][32][64] bf16 tables; h2 written only after attn

  (void)hipFuncSetAttribute((const void*)attn_kernel,
                            hipFuncAttributeMaxDynamicSharedMemorySize, ATTN_SMEM);
  (void)hipFuncSetAttribute((const void*)gemm3_ep<768, 2304, 0>,
                            hipFuncAttributeMaxDynamicSharedMemorySize, GEMM_SMEM);
  (void)hipFuncSetAttribute((const void*)gemm3_ep<768, 768, 1>,
                            hipFuncAttributeMaxDynamicSharedMemorySize, GEMM_SMEM);
  (void)hipFuncSetAttribute((const void*)gemm3_ep<768, 3072, 2>,
                            hipFuncAttributeMaxDynamicSharedMemorySize, GEMM_SMEM);
  (void)hipFuncSetAttribute((const void*)gemm3_ep<3072, 768, 3>,
                            hipFuncAttributeMaxDynamicSharedMemorySize, GEMM_SMEM);

  dim3 tb(32, 8);
  transpose_cvt<<<dim3(2304 / 32, 768 / 32), tb, 0, stream>>>(qkvw, qkvwT, 768, 2304);
  transpose_cvt<<<dim3(768 / 32, 768 / 32),  tb, 0, stream>>>(pjw, projwT, 768, 768);
  transpose_cvt<<<dim3(3072 / 32, 768 / 32), tb, 0, stream>>>(f1w, fc1wT, 768, 3072);
  transpose_cvt<<<dim3(768 / 32, 3072 / 32), tb, 0, stream>>>(f2w, fc2wT, 3072, 768);
  cvt_rpb<<<16, 256, 0, stream>>>(rph, rpw, rpb);

  ln_kernel<true><<<MROWS, 256, 0, stream>>>(x, ln1s, ln1b, xw);

  { Epi e{}; e.bias = qkvb; e.q = qbuf; e.k = kbuf; e.v = vtb;
    gemm3_ep<768, 2304, 0><<<98 * 9, 512, GEMM_SMEM, stream>>>(xw, qkvwT, e); }

  attn_kernel<<<1536, 256, ATTN_SMEM, stream>>>(qbuf, kbuf, vtb, rpb, abuf);

  { Epi e{}; e.bias = pjb; e.x = x; e.outf = out;
    gemm3_ep<768, 768, 1><<<98 * 3, 512, GEMM_SMEM, stream>>>(abuf, projwT, e); }

  ln_kernel<false><<<MROWS, 256, 0, stream>>>(out, ln2s, ln2b, h2);

  { Epi e{}; e.bias = f1b; e.o16 = h1;
    gemm3_ep<768, 3072, 2><<<98 * 12, 512, GEMM_SMEM, stream>>>(h2, fc1wT, e); }

  { Epi e{}; e.bias = f2b_; e.outf = out;
    gemm3_ep<3072, 768, 3><<<98 * 3, 512, GEMM_SMEM, stream>>>(h1, fc2wT, e); }
}

// Round 8
// 909.378 us; speedup vs baseline: 1.1520x; 1.1520x over previous
//
#include <hip/hip_runtime.h>
#include <stdint.h>

typedef unsigned short u16;
typedef __bf16 bf16x8 __attribute__((ext_vector_type(8)));
typedef float f32x4 __attribute__((ext_vector_type(4)));

#define DEVI __device__ __forceinline__

static constexpr int DIM = 768;
static constexpr int SEQL = 3136;   // 56*56
static constexpr int MROWS = 25088; // 8*3136
static constexpr int HEADS = 12;
static constexpr int HD = 64;
static constexpr int NW = 196;      // tokens per window
static constexpr float QSCALE = 0.125f; // 64^-0.5
// attn LDS: sK [208][64]u16 26624 + sP 4*[16][232]u16 29696 + sT 4*[16][64]f32 16384
static constexpr int ATTN_SMEM = 72704;
static constexpr int GEMM_SMEM = 65536; // 2 bufs x (A 16KB + B 16KB)

DEVI float b2f(u16 u) { union { unsigned i; float f; } v; v.i = ((unsigned)u) << 16; return v.f; }
DEVI u16 f2b(float f) { union { float f; unsigned u; } v; v.f = f; return (u16)((v.u + 0x7FFFu + ((v.u >> 16) & 1u)) >> 16); }

DEVI void gl_lds16(const void* g, void* l) {
  __builtin_amdgcn_global_load_lds((const __attribute__((address_space(1))) void*)g,
                                   (__attribute__((address_space(3))) void*)l, 16, 0, 0);
}

// 8B-aligned global bf16x8 load (two dwordx2)
DEVI bf16x8 ldg_b8(const u16* p) {
  union { uint4 u; bf16x8 v; } r;
  const uint2* p2 = (const uint2*)p;
  uint2 lo = p2[0], hi = p2[1];
  r.u.x = lo.x; r.u.y = lo.y; r.u.z = hi.x; r.u.w = hi.y;
  return r.v;
}

// ---------------- weight transpose + f32->bf16 convert: W[K][N] -> Wt[N][K] ---------------
__global__ __launch_bounds__(256) void transpose_cvt(const float* __restrict__ in,
                                                     u16* __restrict__ out, int K, int N) {
  __shared__ float t[32][33];
  int n0 = blockIdx.x * 32, k0 = blockIdx.y * 32;
  int tx = threadIdx.x, ty = threadIdx.y; // (32,8)
  #pragma unroll
  for (int i = ty; i < 32; i += 8) t[i][tx] = in[(size_t)(k0 + i) * N + n0 + tx];
  __syncthreads();
  #pragma unroll
  for (int i = ty; i < 32; i += 8) out[(size_t)(n0 + i) * K + k0 + tx] = f2b(t[tx][i]);
}

// ---------------- rel-pos tables f32 [27][64] -> bf16 [2][32][64] (rows>=27 zero) --------
__global__ __launch_bounds__(256) void cvt_rpb(const float* __restrict__ rph,
                                               const float* __restrict__ rpw,
                                               u16* __restrict__ rpb) {
  int i = blockIdx.x * 256 + threadIdx.x;  // 0..4095
  int tbl = i >> 11, r = (i >> 6) & 31, c = i & 63;
  float v = (r < 27) ? (tbl ? rpw : rph)[r * 64 + c] : 0.f;
  rpb[i] = f2b(v);
}

// ---------------- layernorm (768 cols); REMAP=window-partition the output row ---------------
template<bool REMAP>
__global__ __launch_bounds__(256) void ln_kernel(const float* __restrict__ xin,
                                                 const float* __restrict__ g,
                                                 const float* __restrict__ bb,
                                                 u16* __restrict__ outw) {
  __shared__ float red[8];
  const int r = blockIdx.x;
  const int tid = threadIdx.x;
  const float* xr = xin + (size_t)r * DIM;
  float v0 = xr[tid], v1 = xr[tid + 256], v2 = xr[tid + 512];
  float s1 = v0 + v1 + v2;
  float s2 = v0 * v0 + v1 * v1 + v2 * v2;
  #pragma unroll
  for (int o = 32; o > 0; o >>= 1) { s1 += __shfl_down(s1, o); s2 += __shfl_down(s2, o); }
  const int l = tid & 63, w = tid >> 6;
  if (l == 0) { red[w] = s1; red[w + 4] = s2; }
  __syncthreads();
  float ts = red[0] + red[1] + red[2] + red[3];
  float tss = red[4] + red[5] + red[6] + red[7];
  float mean = ts * (1.f / 768.f);
  float var = tss * (1.f / 768.f) - mean * mean;
  float rstd = rsqrtf(var + 1e-5f);
  size_t orow;
  if constexpr (REMAP) {
    int b = r / SEQL, s = r % SEQL;
    int h = s / 56, ww = s % 56;
    orow = (size_t)(b * 16 + (h / 14) * 4 + (ww / 14)) * NW + (h % 14) * 14 + (ww % 14);
  } else {
    orow = (size_t)r;
  }
  u16* orp = outw + orow * DIM;
  orp[tid]       = f2b((v0 - mean) * rstd * g[tid]       + bb[tid]);
  orp[tid + 256] = f2b((v1 - mean) * rstd * g[tid + 256] + bb[tid + 256]);
  orp[tid + 512] = f2b((v2 - mean) * rstd * g[tid + 512] + bb[tid + 512]);
}

// ------- GEMM v4: 128x128 tile, 4 waves, BK=64, dbuf, 2 blocks/CU, supertile L2 swizzle ----
struct Epi {
  const float* bias;
  const float* x;   // proj: residual input (f32)
  float* outf;      // proj/fc2: f32 out (d_out)
  u16* q; u16* k; u16* v; // qkv outputs (v transposed: [wh][64][196])
  u16* o16;         // fc1 out
};

#define MFMA_BF16 __builtin_amdgcn_mfma_f32_16x16x32_bf16

template<int K, int N, int EPI>
__global__ __launch_bounds__(256, 2)
void gemm4_ep(const u16* __restrict__ A, const u16* __restrict__ Bt, Epi ep) {
  extern __shared__ __align__(16) char gsm[];
  // buffer b (b=0,1): A at gsm + b*32768, B at gsm + b*32768 + 16384

  constexpr int NBN = N / 128;           // 24 / 18 / 6 / 6 -> all divisible by 6
  constexpr int NSTC = NBN / 6;
  constexpr int NKT = K / 64;

  const int tid = threadIdx.x;
  const int l = tid & 63, w = tid >> 6;
  const int lr = l & 15, lg = l >> 4;

  // XCD-contiguous swizzle (nwg % 8 == 0 for all our grids) + 7x6 supertile decode.
  // Panels: 128 rows x K x 2B = 196KB (K=768); 13 panels/supertile = 2.5MB < 4MB L2.
  const int nwg = gridDim.x;
  const int cpx = nwg >> 3;
  const int wg = (blockIdx.x & 7) * cpx + (blockIdx.x >> 3);
  const int st = wg / 42, r42 = wg - st * 42;
  const int bm = (st / NSTC) * 7 + r42 / 6;
  const int bn = (st - (st / NSTC) * NSTC) * 6 + r42 - (r42 / 6) * 6;
  const int wm = (w >> 1) * 64, wn = (w & 1) * 64;   // wave tile 64x64

  const u16* Ab = A + (size_t)bm * 128 * K;
  const u16* Bb = Bt + (size_t)bn * 128 * K;

  // staging: pass p covers rows [32p, 32p+32); thread row = p*32 + (tid>>3), phys 16B-slot
  // tid&7 holds logical slot (tid&7)^(row&7) -> pre-swizzled source, linear LDS dest (T2).
  int srcoff[4];
  #pragma unroll
  for (int p = 0; p < 4; ++p) {
    int row = p * 32 + (tid >> 3);
    srcoff[p] = row * K + (((tid & 7) ^ (row & 7)) << 3);
  }

  #define STG(kt, buf) do {                                                      \
    char* _bA = gsm + (buf) * 32768;                                             \
    char* _bB = _bA + 16384;                                                     \
    _Pragma("unroll")                                                            \
    for (int _p = 0; _p < 4; ++_p)                                               \
      gl_lds16(Ab + srcoff[_p] + (size_t)(kt) * 64, _bA + _p * 4096 + tid * 16); \
    _Pragma("unroll")                                                            \
    for (int _p = 0; _p < 4; ++_p)                                               \
      gl_lds16(Bb + srcoff[_p] + (size_t)(kt) * 64, _bB + _p * 4096 + tid * 16); \
  } while (0)

  const int p0 = lg ^ (lr & 7);   // phys slot, k-slice 0
  const int p1 = p0 ^ 4;          // phys slot, k-slice 1

  f32x4 zero4 = {0.f, 0.f, 0.f, 0.f};
  f32x4 acc[4][4];
  #pragma unroll
  for (int i = 0; i < 4; ++i)
    #pragma unroll
    for (int j = 0; j < 4; ++j) acc[i][j] = zero4;

  STG(0, 0);
  STG(1, 1);

  for (int t = 0; t < NKT; ++t) {
    const u16* cA = (const u16*)(gsm + (t & 1) * 32768);
    const u16* cB = cA + 8192;   // 16384 bytes / 2

    // tile t's 8 loads are the oldest; allow next tile's 8 to stay in flight
    if (t + 1 < NKT) asm volatile("s_waitcnt vmcnt(8)" ::: "memory");
    else             asm volatile("s_waitcnt vmcnt(0)" ::: "memory");
    __builtin_amdgcn_s_barrier();

    bf16x8 af[4][2], bf[4][2];
    #pragma unroll
    for (int mf = 0; mf < 4; ++mf) {
      af[mf][0] = *(const bf16x8*)(cA + (wm + mf * 16 + lr) * 64 + p0 * 8);
      af[mf][1] = *(const bf16x8*)(cA + (wm + mf * 16 + lr) * 64 + p1 * 8);
    }
    #pragma unroll
    for (int nf = 0; nf < 4; ++nf) {
      bf[nf][0] = *(const bf16x8*)(cB + (wn + nf * 16 + lr) * 64 + p0 * 8);
      bf[nf][1] = *(const bf16x8*)(cB + (wn + nf * 16 + lr) * 64 + p1 * 8);
    }
    __builtin_amdgcn_s_setprio(1);
    #pragma unroll
    for (int mf = 0; mf < 4; ++mf)
      #pragma unroll
      for (int nf = 0; nf < 4; ++nf) {
        acc[mf][nf] = MFMA_BF16(af[mf][0], bf[nf][0], acc[mf][nf], 0, 0, 0);
        acc[mf][nf] = MFMA_BF16(af[mf][1], bf[nf][1], acc[mf][nf], 0, 0, 0);
      }
    __builtin_amdgcn_s_setprio(0);
    __builtin_amdgcn_s_barrier();           // all waves done reading buf (t&1)

    if (t + 2 < NKT) STG(t + 2, t & 1);     // refill the buffer just drained
  }
  #undef STG

  // ---- epilogue (wave tile 64x64 at (wm,wn)) ----
  const int mrow0 = bm * 128 + wm + lg * 4;
  const int ncol0 = bn * 128 + wn + lr;
  #pragma unroll
  for (int mf = 0; mf < 4; ++mf) {
    #pragma unroll
    for (int nf = 0; nf < 4; ++nf) {
      #pragma unroll
      for (int e = 0; e < 4; ++e) {
        int rr = mrow0 + mf * 16 + e;
        int c = ncol0 + nf * 16;
        float v = acc[mf][nf][e] + ep.bias[c];
        if constexpr (EPI == 0) { // qkv scatter; v goes out transposed [wh][d][pos]
          int which = c / DIM;
          int hdc = c - which * DIM;
          int head = hdc >> 6, d = hdc & 63;
          int win = rr / NW, pos = rr - win * NW;
          size_t wh = (size_t)win * HEADS + head;
          if (which == 0)      ep.q[(wh * NW + pos) * HD + d] = f2b(v * QSCALE);
          else if (which == 1) ep.k[(wh * NW + pos) * HD + d] = f2b(v);
          else                 ep.v[(wh * HD + d) * NW + pos] = f2b(v);
        } else if constexpr (EPI == 1) { // proj: window-reverse + residual -> f32 d_out
          int win = rr / NW, pos = rr - win * NW;
          int b = win >> 4, wi = win & 15;
          int hh = (wi >> 2) * 14 + pos / 14;
          int ww = (wi & 3) * 14 + pos % 14;
          size_t orow = (size_t)b * SEQL + hh * 56 + ww;
          ep.outf[orow * DIM + c] = ep.x[orow * DIM + c] + v;
        } else if constexpr (EPI == 2) { // fc1: exact GELU -> bf16
          float gg = 0.5f * v * (1.f + erff(v * 0.70710678118654752f));
          ep.o16[(size_t)rr * N + c] = f2b(gg);
        } else { // fc2: residual with d_out (x1), write f32
          size_t idxo = (size_t)rr * N + c;
          ep.outf[idxo] = ep.outf[idxo] + v;
        }
      }
    }
  }
}

// ---------------- fused window attention v3: one 4-wave block per (win*head) ------------
__global__ __launch_bounds__(256, 2)
void attn_kernel(const u16* __restrict__ qbuf, const u16* __restrict__ kbuf,
                 const u16* __restrict__ vt, const u16* __restrict__ rpb,
                 u16* __restrict__ abuf) {
  extern __shared__ __align__(16) char smem[];
  u16* sK = (u16*)smem;                  // [208][64], 16B-slot s -> s^(row&7)
  u16* sP = (u16*)(smem + 26624);        // 4 x [16][232]
  float* sT = (float*)(smem + 56320);    // 4 x [16][64]: cols 0..26 h-term, 32..58 w-term

  const int tid = threadIdx.x;
  const int l = tid & 63, w = tid >> 6;
  const int lr = l & 15, lg = l >> 4;
  const int wh = blockIdx.x;             // win*12 + head
  const int win = wh / HEADS, head = wh - win * HEADS;

  const u16* Qg = qbuf + (size_t)wh * (NW * HD);
  const u16* Kg = kbuf + (size_t)wh * (NW * HD);
  const u16* Vg = vt + (size_t)wh * (HD * NW);   // [64][196]

  for (int t = tid; t < 1664; t += 256) {
    int r8 = t >> 3, c8 = t & 7;
    int s = (t & ~7) | (c8 ^ (r8 & 7));
    if (s >= 1568) s &= 1023;
    gl_lds16(Kg + s * 8, (char*)sK + t * 16);
  }
  __syncthreads();

  f32x4 zero4 = {0.f, 0.f, 0.f, 0.f};
  u16* myP = sP + w * (16 * 232);
  float* myT = sT + w * (16 * 64);

  for (int c = 0; c < 4; ++c) {
    const int chunk = w + 4 * c;
    if (chunk > 12) break;

    int qrow = chunk * 16 + lr; if (qrow > 195) qrow = 195;
    bf16x8 aq0 = *(const bf16x8*)(Qg + (size_t)qrow * HD + lg * 8);
    bf16x8 aq1 = *(const bf16x8*)(Qg + (size_t)qrow * HD + 32 + lg * 8);

    f32x4 th[2], tw[2];
    #pragma unroll
    for (int nf2 = 0; nf2 < 2; ++nf2) {
      const u16* bh = rpb + (nf2 * 16 + lr) * 64;
      const u16* bw = rpb + 2048 + (nf2 * 16 + lr) * 64;
      f32x4 a = zero4, b = zero4;
      a = MFMA_BF16(aq0, *(const bf16x8*)(bh + lg * 8), a, 0, 0, 0);
      a = MFMA_BF16(aq1, *(const bf16x8*)(bh + 32 + lg * 8), a, 0, 0, 0);
      b = MFMA_BF16(aq0, *(const bf16x8*)(bw + lg * 8), b, 0, 0, 0);
      b = MFMA_BF16(aq1, *(const bf16x8*)(bw + 32 + lg * 8), b, 0, 0, 0);
      th[nf2] = a; tw[nf2] = b;
    }
    #pragma unroll
    for (int nf2 = 0; nf2 < 2; ++nf2)
      #pragma unroll
      for (int e = 0; e < 4; ++e) {
        myT[(lg * 4 + e) * 64 + nf2 * 16 + lr]      = th[nf2][e];
        myT[(lg * 4 + e) * 64 + 32 + nf2 * 16 + lr] = tw[nf2][e];
      }

    f32x4 accs[13];
    #pragma unroll
    for (int nf = 0; nf < 13; ++nf) {
      int krow = nf * 16 + lr;
      int ksw = (krow & 7) << 3;
      bf16x8 b0 = *(const bf16x8*)(sK + krow * 64 + ((lg * 8) ^ ksw));
      bf16x8 b1 = *(const bf16x8*)(sK + krow * 64 + ((32 + lg * 8) ^ ksw));
      f32x4 cc = zero4;
      cc = MFMA_BF16(aq0, b0, cc, 0, 0, 0);
      cc = MFMA_BF16(aq1, b1, cc, 0, 0, 0);
      accs[nf] = cc;
    }

    int ihv[4], iwv[4];
    #pragma unroll
    for (int e = 0; e < 4; ++e) {
      int gi = chunk * 16 + lg * 4 + e;
      ihv[e] = (gi * 9363) >> 17;
      iwv[e] = gi - ihv[e] * 14;
    }
    float mrow[4] = {-3e38f, -3e38f, -3e38f, -3e38f};
    #pragma unroll
    for (int nf = 0; nf < 13; ++nf) {
      int j = nf * 16 + lr;
      int jh = (j * 9363) >> 17;
      int jw = j - jh * 14;
      #pragma unroll
      for (int e = 0; e < 4; ++e) {
        int ic = lg * 4 + e;
        float s = accs[nf][e]
                + myT[ic * 64 + ((ihv[e] - jh + 13) & 63)]
                + myT[ic * 64 + 32 + (iwv[e] - jw + 13)];
        if (nf == 12 && lr >= 4) s = -1e30f;
        accs[nf][e] = s;
        mrow[e] = fmaxf(mrow[e], s);
      }
    }
    #pragma unroll
    for (int e = 0; e < 4; ++e) {
      float v = mrow[e];
      v = fmaxf(v, __shfl_xor(v, 1)); v = fmaxf(v, __shfl_xor(v, 2));
      v = fmaxf(v, __shfl_xor(v, 4)); v = fmaxf(v, __shfl_xor(v, 8));
      mrow[e] = v;
    }
    float ssum[4] = {0.f, 0.f, 0.f, 0.f};
    #pragma unroll
    for (int nf = 0; nf < 13; ++nf)
      #pragma unroll
      for (int e = 0; e < 4; ++e) {
        float p = __expf(accs[nf][e] - mrow[e]);
        accs[nf][e] = p;
        ssum[e] += p;
      }
    #pragma unroll
    for (int e = 0; e < 4; ++e) {
      float v = ssum[e];
      v += __shfl_xor(v, 1); v += __shfl_xor(v, 2);
      v += __shfl_xor(v, 4); v += __shfl_xor(v, 8);
      ssum[e] = 1.f / v;
    }
    #pragma unroll
    for (int nf = 0; nf < 13; ++nf)
      #pragma unroll
      for (int e = 0; e < 4; ++e)
        myP[(lg * 4 + e) * 232 + nf * 16 + lr] = f2b(accs[nf][e] * ssum[e]);
    #pragma unroll
    for (int e = 0; e < 4; ++e)
      myP[(lg * 4 + e) * 232 + 208 + lr] = 0;

    f32x4 acco[4];
    #pragma unroll
    for (int nf = 0; nf < 4; ++nf) acco[nf] = zero4;
    #pragma unroll
    for (int ks = 0; ks < 7; ++ks) {
      bf16x8 ap = *(const bf16x8*)(myP + lr * 232 + ks * 32 + lg * 8);
      #pragma unroll
      for (int nf = 0; nf < 4; ++nf) {
        bf16x8 bv = ldg_b8(Vg + (size_t)(nf * 16 + lr) * NW + ks * 32 + lg * 8);
        acco[nf] = MFMA_BF16(ap, bv, acco[nf], 0, 0, 0);
      }
    }
    u16* ob = abuf + (size_t)win * NW * DIM + head * HD;
    #pragma unroll
    for (int nf = 0; nf < 4; ++nf)
      #pragma unroll
      for (int e = 0; e < 4; ++e) {
        int row = chunk * 16 + lg * 4 + e;
        if (row < 196) ob[(size_t)row * DIM + nf * 16 + lr] = f2b(acco[nf][e]);
      }
  }
}

// ---------------- host launch ---------------
extern "C" void kernel_launch(void* const* d_in, const int* in_sizes, int n_in,
                              void* d_out, int out_size, void* d_ws, size_t ws_size,
                              hipStream_t stream) {
  (void)in_sizes; (void)n_in; (void)out_size; (void)ws_size;
  const float* x    = (const float*)d_in[0];
  const float* ln1s = (const float*)d_in[1];
  const float* ln1b = (const float*)d_in[2];
  const float* qkvw = (const float*)d_in[3];
  const float* qkvb = (const float*)d_in[4];
  const float* rph  = (const float*)d_in[5];
  const float* rpw  = (const float*)d_in[6];
  const float* pjw  = (const float*)d_in[7];
  const float* pjb  = (const float*)d_in[8];
  const float* ln2s = (const float*)d_in[9];
  const float* ln2b = (const float*)d_in[10];
  const float* f1w  = (const float*)d_in[11];
  const float* f1b  = (const float*)d_in[12];
  const float* f2w  = (const float*)d_in[13];
  const float* f2b_ = (const float*)d_in[14];
  float* out = (float*)d_out;

  char* ws = (char*)d_ws;
  u16* qkvwT = (u16*)ws;              // [2304][768]
  u16* projwT = qkvwT + 1769472;      // [768][768]
  u16* fc1wT  = qkvwT + 2359296;      // [3072][768]
  u16* fc2wT  = qkvwT + 4718592;      // [768][3072]
  u16* xw   = (u16*)(ws + 14155776);  // [25088][768]
  u16* qbuf = (u16*)(ws + 52690944);  // [1536][196][64]
  u16* kbuf = qbuf + 19267584;
  u16* vtb  = kbuf + 19267584;        // [1536][64][196]
  u16* h2   = (u16*)(ws + 168296448); // [25088][768]
  u16* abuf = xw;                     // alias (xw dead after qkv gemm)
  u16* h1   = xw;                     // [25088][3072] spans xw+q+k+vT regions (all dead)
  u16* rpb  = h2;                     // [2][32][64] bf16 tables; h2 written only after attn

  (void)hipFuncSetAttribute((const void*)attn_kernel,
                            hipFuncAttributeMaxDynamicSharedMemorySize, ATTN_SMEM);
  (void)hipFuncSetAttribute((const void*)gemm4_ep<768, 2304, 0>,
                            hipFuncAttributeMaxDynamicSharedMemorySize, GEMM_SMEM);
  (void)hipFuncSetAttribute((const void*)gemm4_ep<768, 768, 1>,
                            hipFuncAttributeMaxDynamicSharedMemorySize, GEMM_SMEM);
  (void)hipFuncSetAttribute((const void*)gemm4_ep<768, 3072, 2>,
                            hipFuncAttributeMaxDynamicSharedMemorySize, GEMM_SMEM);
  (void)hipFuncSetAttribute((const void*)gemm4_ep<3072, 768, 3>,
                            hipFuncAttributeMaxDynamicSharedMemorySize, GEMM_SMEM);

  dim3 tb(32, 8);
  transpose_cvt<<<dim3(2304 / 32, 768 / 32), tb, 0, stream>>>(qkvw, qkvwT, 768, 2304);
  transpose_cvt<<<dim3(768 / 32, 768 / 32),  tb, 0, stream>>>(pjw, projwT, 768, 768);
  transpose_cvt<<<dim3(3072 / 32, 768 / 32), tb, 0, stream>>>(f1w, fc1wT, 768, 3072);
  transpose_cvt<<<dim3(768 / 32, 3072 / 32), tb, 0, stream>>>(f2w, fc2wT, 3072, 768);
  cvt_rpb<<<16, 256, 0, stream>>>(rph, rpw, rpb);

  ln_kernel<true><<<MROWS, 256, 0, stream>>>(x, ln1s, ln1b, xw);

  { Epi e{}; e.bias = qkvb; e.q = qbuf; e.k = kbuf; e.v = vtb;
    gemm4_ep<768, 2304, 0><<<196 * 18, 256, GEMM_SMEM, stream>>>(xw, qkvwT, e); }

  attn_kernel<<<1536, 256, ATTN_SMEM, stream>>>(qbuf, kbuf, vtb, rpb, abuf);

  { Epi e{}; e.bias = pjb; e.x = x; e.outf = out;
    gemm4_ep<768, 768, 1><<<196 * 6, 256, GEMM_SMEM, stream>>>(abuf, projwT, e); }

  ln_kernel<false><<<MROWS, 256, 0, stream>>>(out, ln2s, ln2b, h2);

  { Epi e{}; e.bias = f1b; e.o16 = h1;
    gemm4_ep<768, 3072, 2><<<196 * 24, 256, GEMM_SMEM, stream>>>(h2, fc1wT, e); }

  { Epi e{}; e.bias = f2b_; e.outf = out;
    gemm4_ep<3072, 768, 3><<<196 * 6, 256, GEMM_SMEM, stream>>>(h1, fc2wT, e); }
}

// Round 9
// 898.342 us; speedup vs baseline: 1.1662x; 1.0123x over previous
//
#include <hip/hip_runtime.h>
#include <stdint.h>

typedef unsigned short u16;
typedef __bf16 bf16x8 __attribute__((ext_vector_type(8)));
typedef float f32x4 __attribute__((ext_vector_type(4)));
typedef unsigned uint32x4 __attribute__((ext_vector_type(4)));

#define DEVI __device__ __forceinline__

static constexpr int DIM = 768;
static constexpr int SEQL = 3136;   // 56*56
static constexpr int MROWS = 25088; // 8*3136
static constexpr int HEADS = 12;
static constexpr int HD = 64;
static constexpr int NW = 196;      // tokens per window
static constexpr float QSCALE = 0.125f; // 64^-0.5
// attn LDS: sK [208][64]u16 26624 + sP 4*[16][232]u16 29696 + sT 4*[16][64]f32 16384
static constexpr int ATTN_SMEM = 72704;
static constexpr int GEMM_SMEM = 67584; // max(2 bufs x 32KB, 4 waves x [64][66] f32)

DEVI float b2f(u16 u) { union { unsigned i; float f; } v; v.i = ((unsigned)u) << 16; return v.f; }
DEVI u16 f2b(float f) { union { float f; unsigned u; } v; v.f = f; return (u16)((v.u + 0x7FFFu + ((v.u >> 16) & 1u)) >> 16); }
DEVI unsigned pack2(float a, float b) { return (unsigned)f2b(a) | ((unsigned)f2b(b) << 16); }

DEVI void gl_lds16(const void* g, void* l) {
  __builtin_amdgcn_global_load_lds((const __attribute__((address_space(1))) void*)g,
                                   (__attribute__((address_space(3))) void*)l, 16, 0, 0);
}

// 8B-aligned global bf16x8 load (two dwordx2)
DEVI bf16x8 ldg_b8(const u16* p) {
  union { uint4 u; bf16x8 v; } r;
  const uint2* p2 = (const uint2*)p;
  uint2 lo = p2[0], hi = p2[1];
  r.u.x = lo.x; r.u.y = lo.y; r.u.z = hi.x; r.u.w = hi.y;
  return r.v;
}

// ---------------- weight transpose + f32->bf16 convert: W[K][N] -> Wt[N][K] ---------------
__global__ __launch_bounds__(256) void transpose_cvt(const float* __restrict__ in,
                                                     u16* __restrict__ out, int K, int N) {
  __shared__ float t[32][33];
  int n0 = blockIdx.x * 32, k0 = blockIdx.y * 32;
  int tx = threadIdx.x, ty = threadIdx.y; // (32,8)
  #pragma unroll
  for (int i = ty; i < 32; i += 8) t[i][tx] = in[(size_t)(k0 + i) * N + n0 + tx];
  __syncthreads();
  #pragma unroll
  for (int i = ty; i < 32; i += 8) out[(size_t)(n0 + i) * K + k0 + tx] = f2b(t[tx][i]);
}

// ---------------- rel-pos tables f32 [27][64] -> bf16 [2][32][64] (rows>=27 zero) --------
__global__ __launch_bounds__(256) void cvt_rpb(const float* __restrict__ rph,
                                               const float* __restrict__ rpw,
                                               u16* __restrict__ rpb) {
  int i = blockIdx.x * 256 + threadIdx.x;  // 0..4095
  int tbl = i >> 11, r = (i >> 6) & 31, c = i & 63;
  float v = (r < 27) ? (tbl ? rpw : rph)[r * 64 + c] : 0.f;
  rpb[i] = f2b(v);
}

// ---------------- layernorm (768 cols); REMAP=window-partition the output row ---------------
template<bool REMAP>
__global__ __launch_bounds__(256) void ln_kernel(const float* __restrict__ xin,
                                                 const float* __restrict__ g,
                                                 const float* __restrict__ bb,
                                                 u16* __restrict__ outw) {
  __shared__ float red[8];
  const int r = blockIdx.x;
  const int tid = threadIdx.x;
  const float* xr = xin + (size_t)r * DIM;
  float v0 = xr[tid], v1 = xr[tid + 256], v2 = xr[tid + 512];
  float s1 = v0 + v1 + v2;
  float s2 = v0 * v0 + v1 * v1 + v2 * v2;
  #pragma unroll
  for (int o = 32; o > 0; o >>= 1) { s1 += __shfl_down(s1, o); s2 += __shfl_down(s2, o); }
  const int l = tid & 63, w = tid >> 6;
  if (l == 0) { red[w] = s1; red[w + 4] = s2; }
  __syncthreads();
  float ts = red[0] + red[1] + red[2] + red[3];
  float tss = red[4] + red[5] + red[6] + red[7];
  float mean = ts * (1.f / 768.f);
  float var = tss * (1.f / 768.f) - mean * mean;
  float rstd = rsqrtf(var + 1e-5f);
  size_t orow;
  if constexpr (REMAP) {
    int b = r / SEQL, s = r % SEQL;
    int h = s / 56, ww = s % 56;
    orow = (size_t)(b * 16 + (h / 14) * 4 + (ww / 14)) * NW + (h % 14) * 14 + (ww % 14);
  } else {
    orow = (size_t)r;
  }
  u16* orp = outw + orow * DIM;
  orp[tid]       = f2b((v0 - mean) * rstd * g[tid]       + bb[tid]);
  orp[tid + 256] = f2b((v1 - mean) * rstd * g[tid + 256] + bb[tid + 256]);
  orp[tid + 512] = f2b((v2 - mean) * rstd * g[tid + 512] + bb[tid + 512]);
}

// ------- GEMM v5: 128x128 tile, 4 waves, BK=64, dbuf, supertile L2 swizzle,
//         epilogue via LDS transpose + wide nontemporal stores --------------------------
struct Epi {
  const float* bias;
  const float* x;   // proj: residual input (f32)
  float* outf;      // proj/fc2: f32 out (d_out)
  u16* q; u16* k; u16* v; // qkv outputs (v transposed: [wh][64][196])
  u16* o16;         // fc1 out
};

#define MFMA_BF16 __builtin_amdgcn_mfma_f32_16x16x32_bf16

template<int K, int N, int EPI>
__global__ __launch_bounds__(256, 2)
void gemm4_ep(const u16* __restrict__ A, const u16* __restrict__ Bt, Epi ep) {
  extern __shared__ __align__(16) char gsm[];
  // K-loop: buffer b (b=0,1): A at gsm + b*32768, B at +16384. Epilogue reuses gsm.

  constexpr int NBN = N / 128;           // 24 / 18 / 6 / 6 -> all divisible by 6
  constexpr int NSTC = NBN / 6;
  constexpr int NKT = K / 64;

  const int tid = threadIdx.x;
  const int l = tid & 63, w = tid >> 6;
  const int lr = l & 15, lg = l >> 4;

  // XCD-contiguous swizzle (nwg % 8 == 0 for all our grids) + 7x6 supertile decode.
  const int nwg = gridDim.x;
  const int cpx = nwg >> 3;
  const int wg = (blockIdx.x & 7) * cpx + (blockIdx.x >> 3);
  const int st = wg / 42, r42 = wg - st * 42;
  const int bm = (st / NSTC) * 7 + r42 / 6;
  const int bn = (st - (st / NSTC) * NSTC) * 6 + r42 - (r42 / 6) * 6;
  const int wm = (w >> 1) * 64, wn = (w & 1) * 64;   // wave tile 64x64

  const u16* Ab = A + (size_t)bm * 128 * K;
  const u16* Bb = Bt + (size_t)bn * 128 * K;

  int srcoff[4];
  #pragma unroll
  for (int p = 0; p < 4; ++p) {
    int row = p * 32 + (tid >> 3);
    srcoff[p] = row * K + (((tid & 7) ^ (row & 7)) << 3);
  }

  #define STG(kt, buf) do {                                                      \
    char* _bA = gsm + (buf) * 32768;                                             \
    char* _bB = _bA + 16384;                                                     \
    _Pragma("unroll")                                                            \
    for (int _p = 0; _p < 4; ++_p)                                               \
      gl_lds16(Ab + srcoff[_p] + (size_t)(kt) * 64, _bA + _p * 4096 + tid * 16); \
    _Pragma("unroll")                                                            \
    for (int _p = 0; _p < 4; ++_p)                                               \
      gl_lds16(Bb + srcoff[_p] + (size_t)(kt) * 64, _bB + _p * 4096 + tid * 16); \
  } while (0)

  const int p0 = lg ^ (lr & 7);   // phys slot, k-slice 0
  const int p1 = p0 ^ 4;          // phys slot, k-slice 1

  f32x4 zero4 = {0.f, 0.f, 0.f, 0.f};
  f32x4 acc[4][4];
  #pragma unroll
  for (int i = 0; i < 4; ++i)
    #pragma unroll
    for (int j = 0; j < 4; ++j) acc[i][j] = zero4;

  STG(0, 0);
  STG(1, 1);

  for (int t = 0; t < NKT; ++t) {
    const u16* cA = (const u16*)(gsm + (t & 1) * 32768);
    const u16* cB = cA + 8192;   // 16384 bytes / 2

    if (t + 1 < NKT) asm volatile("s_waitcnt vmcnt(8)" ::: "memory");
    else             asm volatile("s_waitcnt vmcnt(0)" ::: "memory");
    __builtin_amdgcn_s_barrier();

    bf16x8 af[4][2], bf[4][2];
    #pragma unroll
    for (int mf = 0; mf < 4; ++mf) {
      af[mf][0] = *(const bf16x8*)(cA + (wm + mf * 16 + lr) * 64 + p0 * 8);
      af[mf][1] = *(const bf16x8*)(cA + (wm + mf * 16 + lr) * 64 + p1 * 8);
    }
    #pragma unroll
    for (int nf = 0; nf < 4; ++nf) {
      bf[nf][0] = *(const bf16x8*)(cB + (wn + nf * 16 + lr) * 64 + p0 * 8);
      bf[nf][1] = *(const bf16x8*)(cB + (wn + nf * 16 + lr) * 64 + p1 * 8);
    }
    __builtin_amdgcn_s_setprio(1);
    #pragma unroll
    for (int mf = 0; mf < 4; ++mf)
      #pragma unroll
      for (int nf = 0; nf < 4; ++nf) {
        acc[mf][nf] = MFMA_BF16(af[mf][0], bf[nf][0], acc[mf][nf], 0, 0, 0);
        acc[mf][nf] = MFMA_BF16(af[mf][1], bf[nf][1], acc[mf][nf], 0, 0, 0);
      }
    __builtin_amdgcn_s_setprio(0);
    __builtin_amdgcn_s_barrier();           // all waves done reading buf (t&1)

    if (t + 2 < NKT) STG(t + 2, t & 1);     // refill the buffer just drained
  }
  #undef STG

  // ---- epilogue v2: stage acc to LDS [64][66] f32 per wave (wave-local), then
  //      each lane owns 16 row-contiguous outputs -> wide nontemporal stores. ----
  float* tp = (float*)gsm + w * (64 * 66);
  #pragma unroll
  for (int mf = 0; mf < 4; ++mf)
    #pragma unroll
    for (int nf = 0; nf < 4; ++nf)
      #pragma unroll
      for (int e = 0; e < 4; ++e)
        tp[(mf * 16 + lg * 4 + e) * 66 + nf * 16 + lr] = acc[mf][nf][e];

  const int ccl = (l & 3) * 16;               // my 16-col chunk within the wave tile
  const int cbase = bn * 128 + wn + ccl;      // global col
  f32x4 bs[4];
  #pragma unroll
  for (int jj = 0; jj < 4; ++jj) bs[jj] = *(const f32x4*)(ep.bias + cbase + jj * 4);

  #pragma unroll
  for (int pp = 0; pp < 4; ++pp) {
    const int row = pp * 16 + (l >> 2);
    const int r = bm * 128 + wm + row;
    const int c = cbase;
    f32x4 vv[4];
    #pragma unroll
    for (int jj = 0; jj < 4; ++jj) {
      #pragma unroll
      for (int j2 = 0; j2 < 4; ++j2)
        vv[jj][j2] = tp[row * 66 + ccl + jj * 4 + j2];
      vv[jj] += bs[jj];
    }

    if constexpr (EPI == 0) { // qkv: q/k wide nt; v scalar nt scatter (transposed layout)
      const int which = c / DIM;
      const int hdc = c - which * DIM;
      const int head = hdc >> 6, d0 = hdc & 63;
      const int win = r / NW, pos = r - win * NW;
      const size_t wh = (size_t)win * HEADS + head;
      if (which == 0) {
        uint32x4 o0, o1;
        o0[0] = pack2(vv[0][0] * QSCALE, vv[0][1] * QSCALE);
        o0[1] = pack2(vv[0][2] * QSCALE, vv[0][3] * QSCALE);
        o0[2] = pack2(vv[1][0] * QSCALE, vv[1][1] * QSCALE);
        o0[3] = pack2(vv[1][2] * QSCALE, vv[1][3] * QSCALE);
        o1[0] = pack2(vv[2][0] * QSCALE, vv[2][1] * QSCALE);
        o1[1] = pack2(vv[2][2] * QSCALE, vv[2][3] * QSCALE);
        o1[2] = pack2(vv[3][0] * QSCALE, vv[3][1] * QSCALE);
        o1[3] = pack2(vv[3][2] * QSCALE, vv[3][3] * QSCALE);
        u16* dst = ep.q + (wh * NW + pos) * HD + d0;
        __builtin_nontemporal_store(o0, (uint32x4*)dst);
        __builtin_nontemporal_store(o1, (uint32x4*)(dst + 8));
      } else if (which == 1) {
        uint32x4 o0, o1;
        o0[0] = pack2(vv[0][0], vv[0][1]); o0[1] = pack2(vv[0][2], vv[0][3]);
        o0[2] = pack2(vv[1][0], vv[1][1]); o0[3] = pack2(vv[1][2], vv[1][3]);
        o1[0] = pack2(vv[2][0], vv[2][1]); o1[1] = pack2(vv[2][2], vv[2][3]);
        o1[2] = pack2(vv[3][0], vv[3][1]); o1[3] = pack2(vv[3][2], vv[3][3]);
        u16* dst = ep.k + (wh * NW + pos) * HD + d0;
        __builtin_nontemporal_store(o0, (uint32x4*)dst);
        __builtin_nontemporal_store(o1, (uint32x4*)(dst + 8));
      } else {
        #pragma unroll
        for (int jj = 0; jj < 4; ++jj)
          #pragma unroll
          for (int j2 = 0; j2 < 4; ++j2)
            __builtin_nontemporal_store(f2b(vv[jj][j2]),
                ep.v + (wh * HD + d0 + jj * 4 + j2) * NW + pos);
      }
    } else if constexpr (EPI == 1) { // proj: window-reverse + residual -> f32 d_out
      const int win = r / NW, pos = r - win * NW;
      const int b = win >> 4, wi = win & 15;
      const int hh = (wi >> 2) * 14 + pos / 14;
      const int ww2 = (wi & 3) * 14 + pos % 14;
      const size_t orow = (size_t)b * SEQL + hh * 56 + ww2;
      const f32x4* px = (const f32x4*)(ep.x + orow * DIM + c);
      f32x4* po = (f32x4*)(ep.outf + orow * DIM + c);
      #pragma unroll
      for (int jj = 0; jj < 4; ++jj) {
        f32x4 t2 = px[jj] + vv[jj];
        __builtin_nontemporal_store(t2, po + jj);
      }
    } else if constexpr (EPI == 2) { // fc1: exact GELU -> bf16 wide nt
      float g[16];
      #pragma unroll
      for (int jj = 0; jj < 4; ++jj)
        #pragma unroll
        for (int j2 = 0; j2 < 4; ++j2) {
          float x2 = vv[jj][j2];
          g[jj * 4 + j2] = 0.5f * x2 * (1.f + erff(x2 * 0.70710678118654752f));
        }
      uint32x4 o0, o1;
      o0[0] = pack2(g[0], g[1]);   o0[1] = pack2(g[2], g[3]);
      o0[2] = pack2(g[4], g[5]);   o0[3] = pack2(g[6], g[7]);
      o1[0] = pack2(g[8], g[9]);   o1[1] = pack2(g[10], g[11]);
      o1[2] = pack2(g[12], g[13]); o1[3] = pack2(g[14], g[15]);
      u16* dst = ep.o16 + (size_t)r * N + c;
      __builtin_nontemporal_store(o0, (uint32x4*)dst);
      __builtin_nontemporal_store(o1, (uint32x4*)(dst + 8));
    } else { // fc2: residual with d_out (x1): cached read, nt write
      f32x4* po = (f32x4*)(ep.outf + (size_t)r * N + c);
      #pragma unroll
      for (int jj = 0; jj < 4; ++jj) {
        f32x4 t2 = po[jj] + vv[jj];
        __builtin_nontemporal_store(t2, po + jj);
      }
    }
  }
}

// ---------------- fused window attention v3: one 4-wave block per (win*head) ------------
__global__ __launch_bounds__(256, 2)
void attn_kernel(const u16* __restrict__ qbuf, const u16* __restrict__ kbuf,
                 const u16* __restrict__ vt, const u16* __restrict__ rpb,
                 u16* __restrict__ abuf) {
  extern __shared__ __align__(16) char smem[];
  u16* sK = (u16*)smem;                  // [208][64], 16B-slot s -> s^(row&7)
  u16* sP = (u16*)(smem + 26624);        // 4 x [16][232]
  float* sT = (float*)(smem + 56320);    // 4 x [16][64]: cols 0..26 h-term, 32..58 w-term

  const int tid = threadIdx.x;
  const int l = tid & 63, w = tid >> 6;
  const int lr = l & 15, lg = l >> 4;
  const int wh = blockIdx.x;             // win*12 + head
  const int win = wh / HEADS, head = wh - win * HEADS;

  const u16* Qg = qbuf + (size_t)wh * (NW * HD);
  const u16* Kg = kbuf + (size_t)wh * (NW * HD);
  const u16* Vg = vt + (size_t)wh * (HD * NW);   // [64][196]

  for (int t = tid; t < 1664; t += 256) {
    int r8 = t >> 3, c8 = t & 7;
    int s = (t & ~7) | (c8 ^ (r8 & 7));
    if (s >= 1568) s &= 1023;
    gl_lds16(Kg + s * 8, (char*)sK + t * 16);
  }
  __syncthreads();

  f32x4 zero4 = {0.f, 0.f, 0.f, 0.f};
  u16* myP = sP + w * (16 * 232);
  float* myT = sT + w * (16 * 64);

  for (int c = 0; c < 4; ++c) {
    const int chunk = w + 4 * c;
    if (chunk > 12) break;

    int qrow = chunk * 16 + lr; if (qrow > 195) qrow = 195;
    bf16x8 aq0 = *(const bf16x8*)(Qg + (size_t)qrow * HD + lg * 8);
    bf16x8 aq1 = *(const bf16x8*)(Qg + (size_t)qrow * HD + 32 + lg * 8);

    f32x4 th[2], tw[2];
    #pragma unroll
    for (int nf2 = 0; nf2 < 2; ++nf2) {
      const u16* bh = rpb + (nf2 * 16 + lr) * 64;
      const u16* bw = rpb + 2048 + (nf2 * 16 + lr) * 64;
      f32x4 a = zero4, b = zero4;
      a = MFMA_BF16(aq0, *(const bf16x8*)(bh + lg * 8), a, 0, 0, 0);
      a = MFMA_BF16(aq1, *(const bf16x8*)(bh + 32 + lg * 8), a, 0, 0, 0);
      b = MFMA_BF16(aq0, *(const bf16x8*)(bw + lg * 8), b, 0, 0, 0);
      b = MFMA_BF16(aq1, *(const bf16x8*)(bw + 32 + lg * 8), b, 0, 0, 0);
      th[nf2] = a; tw[nf2] = b;
    }
    #pragma unroll
    for (int nf2 = 0; nf2 < 2; ++nf2)
      #pragma unroll
      for (int e = 0; e < 4; ++e) {
        myT[(lg * 4 + e) * 64 + nf2 * 16 + lr]      = th[nf2][e];
        myT[(lg * 4 + e) * 64 + 32 + nf2 * 16 + lr] = tw[nf2][e];
      }

    f32x4 accs[13];
    #pragma unroll
    for (int nf = 0; nf < 13; ++nf) {
      int krow = nf * 16 + lr;
      int ksw = (krow & 7) << 3;
      bf16x8 b0 = *(const bf16x8*)(sK + krow * 64 + ((lg * 8) ^ ksw));
      bf16x8 b1 = *(const bf16x8*)(sK + krow * 64 + ((32 + lg * 8) ^ ksw));
      f32x4 cc = zero4;
      cc = MFMA_BF16(aq0, b0, cc, 0, 0, 0);
      cc = MFMA_BF16(aq1, b1, cc, 0, 0, 0);
      accs[nf] = cc;
    }

    int ihv[4], iwv[4];
    #pragma unroll
    for (int e = 0; e < 4; ++e) {
      int gi = chunk * 16 + lg * 4 + e;
      ihv[e] = (gi * 9363) >> 17;
      iwv[e] = gi - ihv[e] * 14;
    }
    float mrow[4] = {-3e38f, -3e38f, -3e38f, -3e38f};
    #pragma unroll
    for (int nf = 0; nf < 13; ++nf) {
      int j = nf * 16 + lr;
      int jh = (j * 9363) >> 17;
      int jw = j - jh * 14;
      #pragma unroll
      for (int e = 0; e < 4; ++e) {
        int ic = lg * 4 + e;
        float s = accs[nf][e]
                + myT[ic * 64 + ((ihv[e] - jh + 13) & 63)]
                + myT[ic * 64 + 32 + (iwv[e] - jw + 13)];
        if (nf == 12 && lr >= 4) s = -1e30f;
        accs[nf][e] = s;
        mrow[e] = fmaxf(mrow[e], s);
      }
    }
    #pragma unroll
    for (int e = 0; e < 4; ++e) {
      float v = mrow[e];
      v = fmaxf(v, __shfl_xor(v, 1)); v = fmaxf(v, __shfl_xor(v, 2));
      v = fmaxf(v, __shfl_xor(v, 4)); v = fmaxf(v, __shfl_xor(v, 8));
      mrow[e] = v;
    }
    float ssum[4] = {0.f, 0.f, 0.f, 0.f};
    #pragma unroll
    for (int nf = 0; nf < 13; ++nf)
      #pragma unroll
      for (int e = 0; e < 4; ++e) {
        float p = __expf(accs[nf][e] - mrow[e]);
        accs[nf][e] = p;
        ssum[e] += p;
      }
    #pragma unroll
    for (int e = 0; e < 4; ++e) {
      float v = ssum[e];
      v += __shfl_xor(v, 1); v += __shfl_xor(v, 2);
      v += __shfl_xor(v, 4); v += __shfl_xor(v, 8);
      ssum[e] = 1.f / v;
    }
    #pragma unroll
    for (int nf = 0; nf < 13; ++nf)
      #pragma unroll
      for (int e = 0; e < 4; ++e)
        myP[(lg * 4 + e) * 232 + nf * 16 + lr] = f2b(accs[nf][e] * ssum[e]);
    #pragma unroll
    for (int e = 0; e < 4; ++e)
      myP[(lg * 4 + e) * 232 + 208 + lr] = 0;

    f32x4 acco[4];
    #pragma unroll
    for (int nf = 0; nf < 4; ++nf) acco[nf] = zero4;
    #pragma unroll
    for (int ks = 0; ks < 7; ++ks) {
      bf16x8 ap = *(const bf16x8*)(myP + lr * 232 + ks * 32 + lg * 8);
      #pragma unroll
      for (int nf = 0; nf < 4; ++nf) {
        bf16x8 bv = ldg_b8(Vg + (size_t)(nf * 16 + lr) * NW + ks * 32 + lg * 8);
        acco[nf] = MFMA_BF16(ap, bv, acco[nf], 0, 0, 0);
      }
    }
    u16* ob = abuf + (size_t)win * NW * DIM + head * HD;
    #pragma unroll
    for (int nf = 0; nf < 4; ++nf)
      #pragma unroll
      for (int e = 0; e < 4; ++e) {
        int row = chunk * 16 + lg * 4 + e;
        if (row < 196) ob[(size_t)row * DIM + nf * 16 + lr] = f2b(acco[nf][e]);
      }
  }
}

// ---------------- host launch ---------------
extern "C" void kernel_launch(void* const* d_in, const int* in_sizes, int n_in,
                              void* d_out, int out_size, void* d_ws, size_t ws_size,
                              hipStream_t stream) {
  (void)in_sizes; (void)n_in; (void)out_size; (void)ws_size;
  const float* x    = (const float*)d_in[0];
  const float* ln1s = (const float*)d_in[1];
  const float* ln1b = (const float*)d_in[2];
  const float* qkvw = (const float*)d_in[3];
  const float* qkvb = (const float*)d_in[4];
  const float* rph  = (const float*)d_in[5];
  const float* rpw  = (const float*)d_in[6];
  const float* pjw  = (const float*)d_in[7];
  const float* pjb  = (const float*)d_in[8];
  const float* ln2s = (const float*)d_in[9];
  const float* ln2b = (const float*)d_in[10];
  const float* f1w  = (const float*)d_in[11];
  const float* f1b  = (const float*)d_in[12];
  const float* f2w  = (const float*)d_in[13];
  const float* f2b_ = (const float*)d_in[14];
  float* out = (float*)d_out;

  char* ws = (char*)d_ws;
  u16* qkvwT = (u16*)ws;              // [2304][768]
  u16* projwT = qkvwT + 1769472;      // [768][768]
  u16* fc1wT  = qkvwT + 2359296;      // [3072][768]
  u16* fc2wT  = qkvwT + 4718592;      // [768][3072]
  u16* xw   = (u16*)(ws + 14155776);  // [25088][768]
  u16* qbuf = (u16*)(ws + 52690944);  // [1536][196][64]
  u16* kbuf = qbuf + 19267584;
  u16* vtb  = kbuf + 19267584;        // [1536][64][196]
  u16* h2   = (u16*)(ws + 168296448); // [25088][768]
  u16* abuf = xw;                     // alias (xw dead after qkv gemm)
  u16* h1   = xw;                     // [25088][3072] spans xw+q+k+vT regions (all dead)
  u16* rpb  = h2;                     // [2][32][64] bf16 tables; h2 written only after attn

  (void)hipFuncSetAttribute((const void*)attn_kernel,
                            hipFuncAttributeMaxDynamicSharedMemorySize, ATTN_SMEM);
  (void)hipFuncSetAttribute((const void*)gemm4_ep<768, 2304, 0>,
                            hipFuncAttributeMaxDynamicSharedMemorySize, GEMM_SMEM);
  (void)hipFuncSetAttribute((const void*)gemm4_ep<768, 768, 1>,
                            hipFuncAttributeMaxDynamicSharedMemorySize, GEMM_SMEM);
  (void)hipFuncSetAttribute((const void*)gemm4_ep<768, 3072, 2>,
                            hipFuncAttributeMaxDynamicSharedMemorySize, GEMM_SMEM);
  (void)hipFuncSetAttribute((const void*)gemm4_ep<3072, 768, 3>,
                            hipFuncAttributeMaxDynamicSharedMemorySize, GEMM_SMEM);

  dim3 tb(32, 8);
  transpose_cvt<<<dim3(2304 / 32, 768 / 32), tb, 0, stream>>>(qkvw, qkvwT, 768, 2304);
  transpose_cvt<<<dim3(768 / 32, 768 / 32),  tb, 0, stream>>>(pjw, projwT, 768, 768);
  transpose_cvt<<<dim3(3072 / 32, 768 / 32), tb, 0, stream>>>(f1w, fc1wT, 768, 3072);
  transpose_cvt<<<dim3(768 / 32, 3072 / 32), tb, 0, stream>>>(f2w, fc2wT, 3072, 768);
  cvt_rpb<<<16, 256, 0, stream>>>(rph, rpw, rpb);

  ln_kernel<true><<<MROWS, 256, 0, stream>>>(x, ln1s, ln1b, xw);

  { Epi e{}; e.bias = qkvb; e.q = qbuf; e.k = kbuf; e.v = vtb;
    gemm4_ep<768, 2304, 0><<<196 * 18, 256, GEMM_SMEM, stream>>>(xw, qkvwT, e); }

  attn_kernel<<<1536, 256, ATTN_SMEM, stream>>>(qbuf, kbuf, vtb, rpb, abuf);

  { Epi e{}; e.bias = pjb; e.x = x; e.outf = out;
    gemm4_ep<768, 768, 1><<<196 * 6, 256, GEMM_SMEM, stream>>>(abuf, projwT, e); }

  ln_kernel<false><<<MROWS, 256, 0, stream>>>(out, ln2s, ln2b, h2);

  { Epi e{}; e.bias = f1b; e.o16 = h1;
    gemm4_ep<768, 3072, 2><<<196 * 24, 256, GEMM_SMEM, stream>>>(h2, fc1wT, e); }

  { Epi e{}; e.bias = f2b_; e.outf = out;
    gemm4_ep<3072, 768, 3><<<196 * 6, 256, GEMM_SMEM, stream>>>(h1, fc2wT, e); }
}

// Round 10
// 805.823 us; speedup vs baseline: 1.3000x; 1.1148x over previous
//
#include <hip/hip_runtime.h>
#include <stdint.h>

typedef unsigned short u16;
typedef __bf16 bf16x8 __attribute__((ext_vector_type(8)));
typedef float f32x4 __attribute__((ext_vector_type(4)));
typedef unsigned uint32x4 __attribute__((ext_vector_type(4)));

#define DEVI __device__ __forceinline__

static constexpr int DIM = 768;
static constexpr int SEQL = 3136;   // 56*56
static constexpr int MROWS = 25088; // 8*3136
static constexpr int HEADS = 12;
static constexpr int HD = 64;
static constexpr int NW = 196;      // tokens per window
static constexpr float QSCALE = 0.125f; // 64^-0.5
static constexpr int ATTN_SMEM = 72704;
static constexpr int GEMM_SMEM = 49152; // 3 A-buffers x 16KB; epilogue 4x[32][66]f32=33792 fits

DEVI float b2f(u16 u) { union { unsigned i; float f; } v; v.i = ((unsigned)u) << 16; return v.f; }
DEVI u16 f2b(float f) { union { float f; unsigned u; } v; v.f = f; return (u16)((v.u + 0x7FFFu + ((v.u >> 16) & 1u)) >> 16); }
DEVI unsigned pack2(float a, float b) { return (unsigned)f2b(a) | ((unsigned)f2b(b) << 16); }
DEVI bf16x8 u4bf(uint4 u) { union { uint4 a; bf16x8 b; } c; c.a = u; return c.b; }

DEVI void gl_lds16(const void* g, void* l) {
  __builtin_amdgcn_global_load_lds((const __attribute__((address_space(1))) void*)g,
                                   (__attribute__((address_space(3))) void*)l, 16, 0, 0);
}

// 8B-aligned global bf16x8 load (two dwordx2)
DEVI bf16x8 ldg_b8(const u16* p) {
  union { uint4 u; bf16x8 v; } r;
  const uint2* p2 = (const uint2*)p;
  uint2 lo = p2[0], hi = p2[1];
  r.u.x = lo.x; r.u.y = lo.y; r.u.z = hi.x; r.u.w = hi.y;
  return r.v;
}

// ------- pack W[K][N] f32 -> MFMA-native fragment order bf16:
// out[((bn*NKT + kt)*2 + wn2)*4096 + (nf*2+s)*512 + l*8 + e]
// lane l=(lg<<4)|lr holds n = bn*128+wn2*64+nf*16+lr, k = kt*64+s*32+lg*8+e
__global__ __launch_bounds__(256) void pack_b(const float* __restrict__ in,
                                              u16* __restrict__ out, int K, int N) {
  int f8 = blockIdx.x * 256 + threadIdx.x;   // grid.x = K/16 -> f8 < K*16
  int l = f8 & 63;
  int rest = f8 >> 6;
  int s = rest & 1, nf = (rest >> 1) & 3, wn2 = (rest >> 3) & 1, kt = rest >> 4;
  int bn = blockIdx.y;
  int n = bn * 128 + wn2 * 64 + nf * 16 + (l & 15);
  int kb = kt * 64 + s * 32 + (l >> 4) * 8;
  size_t obase = (((size_t)bn * (K >> 6) + kt) * 2 + wn2) * 4096 + (nf * 2 + s) * 512 + (size_t)l * 8;
  #pragma unroll
  for (int e = 0; e < 8; ++e)
    out[obase + e] = f2b(in[(size_t)(kb + e) * N + n]);
}

// ---------------- rel-pos tables f32 [27][64] -> bf16 [2][32][64] (rows>=27 zero) --------
__global__ __launch_bounds__(256) void cvt_rpb(const float* __restrict__ rph,
                                               const float* __restrict__ rpw,
                                               u16* __restrict__ rpb) {
  int i = blockIdx.x * 256 + threadIdx.x;  // 0..4095
  int tbl = i >> 11, r = (i >> 6) & 31, c = i & 63;
  float v = (r < 27) ? (tbl ? rpw : rph)[r * 64 + c] : 0.f;
  rpb[i] = f2b(v);
}

// ---------------- layernorm (768 cols); REMAP=window-partition the output row ---------------
template<bool REMAP>
__global__ __launch_bounds__(256) void ln_kernel(const float* __restrict__ xin,
                                                 const float* __restrict__ g,
                                                 const float* __restrict__ bb,
                                                 u16* __restrict__ outw) {
  __shared__ float red[8];
  const int r = blockIdx.x;
  const int tid = threadIdx.x;
  const float* xr = xin + (size_t)r * DIM;
  float v0 = xr[tid], v1 = xr[tid + 256], v2 = xr[tid + 512];
  float s1 = v0 + v1 + v2;
  float s2 = v0 * v0 + v1 * v1 + v2 * v2;
  #pragma unroll
  for (int o = 32; o > 0; o >>= 1) { s1 += __shfl_down(s1, o); s2 += __shfl_down(s2, o); }
  const int l = tid & 63, w = tid >> 6;
  if (l == 0) { red[w] = s1; red[w + 4] = s2; }
  __syncthreads();
  float ts = red[0] + red[1] + red[2] + red[3];
  float tss = red[4] + red[5] + red[6] + red[7];
  float mean = ts * (1.f / 768.f);
  float var = tss * (1.f / 768.f) - mean * mean;
  float rstd = rsqrtf(var + 1e-5f);
  size_t orow;
  if constexpr (REMAP) {
    int b = r / SEQL, s = r % SEQL;
    int h = s / 56, ww = s % 56;
    orow = (size_t)(b * 16 + (h / 14) * 4 + (ww / 14)) * NW + (h % 14) * 14 + (ww % 14);
  } else {
    orow = (size_t)r;
  }
  u16* orp = outw + orow * DIM;
  orp[tid]       = f2b((v0 - mean) * rstd * g[tid]       + bb[tid]);
  orp[tid + 256] = f2b((v1 - mean) * rstd * g[tid + 256] + bb[tid + 256]);
  orp[tid + 512] = f2b((v2 - mean) * rstd * g[tid + 512] + bb[tid + 512]);
}

// ------- GEMM v6: 128x128, 4 waves, BK=64. A in 3 rotating LDS buffers (gl_lds, swizzled);
//         B as packed fragments straight from global (L2). 3 blocks/CU. 1 barrier/tile. ----
struct Epi {
  const float* bias;
  const float* x;   // proj: residual input (f32)
  float* outf;      // proj/fc2: f32 out (d_out)
  u16* q; u16* k; u16* v; // qkv outputs (v transposed: [wh][64][196])
  u16* o16;         // fc1 out
};

#define MFMA_BF16 __builtin_amdgcn_mfma_f32_16x16x32_bf16

template<int K, int N, int EPI>
__global__ __launch_bounds__(256, 3)
void gemm6_ep(const u16* __restrict__ A, const u16* __restrict__ Bp, Epi ep) {
  extern __shared__ __align__(16) char gsm[];   // 3 x 16KB A-buffers; epilogue reuse

  constexpr int NBN = N / 128;           // 18 / 6 / 24 / 6 -> divisible by 6
  constexpr int NSTC = NBN / 6;
  constexpr int NKT = K / 64;

  const int tid = threadIdx.x;
  const int l = tid & 63, w = tid >> 6;
  const int lr = l & 15, lg = l >> 4;

  // XCD-contiguous swizzle + 7x6 supertile decode (panel set per supertile fits L2)
  const int nwg = gridDim.x;
  const int cpx = nwg >> 3;
  const int wg = (blockIdx.x & 7) * cpx + (blockIdx.x >> 3);
  const int st = wg / 42, r42 = wg - st * 42;
  const int bm = (st / NSTC) * 7 + r42 / 6;
  const int bn = (st - (st / NSTC) * NSTC) * 6 + r42 - (r42 / 6) * 6;
  const int wm = (w >> 1) * 64, wn = (w & 1) * 64;   // wave tile 64x64

  const u16* Ab = A + (size_t)bm * 128 * K;
  // packed B base for this wave (wn2 = w&1): +t*8192 per K-tile, frag (nf,s) at +(nf*2+s)*512
  const u16* Bw = Bp + (((size_t)bn * NKT) * 2 + (w & 1)) * 4096 + (size_t)l * 8;

  // A staging: 16KB = 1024 slots of 16B; slot si = p*256+tid; row=si>>3; phys=si&7;
  // logical slot = phys^(row&7) -> pre-swizzled source col, linear LDS dest (rule #21).
  int srcoff[4];
  #pragma unroll
  for (int p = 0; p < 4; ++p) {
    int si = p * 256 + tid;
    int row = si >> 3;
    srcoff[p] = row * K + (((si & 7) ^ (row & 7)) << 3);
  }
  #define STG(kt, buf) do {                                                     \
    char* _d = gsm + (buf) * 16384;                                             \
    _Pragma("unroll")                                                           \
    for (int _p = 0; _p < 4; ++_p)                                              \
      gl_lds16(Ab + srcoff[_p] + (size_t)(kt) * 64, _d + _p * 4096 + tid * 16); \
  } while (0)

  const int p0 = lg ^ (lr & 7);   // phys slot, k-slice 0
  const int p1 = p0 ^ 4;          // phys slot, k-slice 1

  f32x4 zero4 = {0.f, 0.f, 0.f, 0.f};
  f32x4 acc[4][4];
  #pragma unroll
  for (int i = 0; i < 4; ++i)
    #pragma unroll
    for (int j = 0; j < 4; ++j) acc[i][j] = zero4;

  STG(0, 0);
  STG(1, 1);

  for (int t = 0; t < NKT; ++t) {
    // wait own A(t) (and older B) complete; leave A(t+1)'s 4 loads in flight
    if (t + 1 < NKT) asm volatile("s_waitcnt vmcnt(4)" ::: "memory");
    else             asm volatile("s_waitcnt vmcnt(0)" ::: "memory");
    __builtin_amdgcn_s_barrier();

    // B fragments for tile t: 8 coalesced dwordx4 from L2
    uint4 braw[4][2];
    const u16* bt = Bw + (size_t)t * 8192;
    #pragma unroll
    for (int nf = 0; nf < 4; ++nf)
      #pragma unroll
      for (int s = 0; s < 2; ++s)
        braw[nf][s] = *(const uint4*)(bt + (nf * 2 + s) * 512);

    if (t + 2 < NKT) STG(t + 2, (t + 2) % 3);   // buffer free: last read at t-1

    const u16* cA = (const u16*)(gsm + (t % 3) * 16384);
    bf16x8 af[4][2];
    #pragma unroll
    for (int mf = 0; mf < 4; ++mf) {
      af[mf][0] = *(const bf16x8*)(cA + (wm + mf * 16 + lr) * 64 + p0 * 8);
      af[mf][1] = *(const bf16x8*)(cA + (wm + mf * 16 + lr) * 64 + p1 * 8);
    }
    __builtin_amdgcn_s_setprio(1);
    #pragma unroll
    for (int mf = 0; mf < 4; ++mf)
      #pragma unroll
      for (int nf = 0; nf < 4; ++nf) {
        acc[mf][nf] = MFMA_BF16(af[mf][0], u4bf(braw[nf][0]), acc[mf][nf], 0, 0, 0);
        acc[mf][nf] = MFMA_BF16(af[mf][1], u4bf(braw[nf][1]), acc[mf][nf], 0, 0, 0);
      }
    __builtin_amdgcn_s_setprio(0);
    // no trailing barrier: 3-buffer rotation makes next stage race-free
  }
  #undef STG

  // ---- epilogue: 2-pass LDS transpose ([32][66] f32 per wave) + wide nt stores ----
  __syncthreads();   // K-loop LDS fully retired before reuse
  float* tp = (float*)(gsm + w * 8448);
  const int ccl = (l & 3) * 16;
  const int cbase = bn * 128 + wn + ccl;
  f32x4 bs[4];
  #pragma unroll
  for (int jj = 0; jj < 4; ++jj) bs[jj] = *(const f32x4*)(ep.bias + cbase + jj * 4);

  #pragma unroll
  for (int q = 0; q < 2; ++q) {
    if (q == 1) { asm volatile("s_waitcnt lgkmcnt(0)" ::: "memory"); __builtin_amdgcn_sched_barrier(0); }
    #pragma unroll
    for (int mf2 = 0; mf2 < 2; ++mf2)
      #pragma unroll
      for (int nf = 0; nf < 4; ++nf)
        #pragma unroll
        for (int e = 0; e < 4; ++e)
          tp[(mf2 * 16 + lg * 4 + e) * 66 + nf * 16 + lr] = acc[q * 2 + mf2][nf][e];
    asm volatile("s_waitcnt lgkmcnt(0)" ::: "memory");
    __builtin_amdgcn_sched_barrier(0);

    #pragma unroll
    for (int pp = 0; pp < 2; ++pp) {
      const int rowl = pp * 16 + (l >> 2);
      const int r = bm * 128 + wm + q * 32 + rowl;
      const int c = cbase;
      f32x4 vv[4];
      #pragma unroll
      for (int jj = 0; jj < 4; ++jj) {
        #pragma unroll
        for (int j2 = 0; j2 < 4; ++j2)
          vv[jj][j2] = tp[rowl * 66 + ccl + jj * 4 + j2];
        vv[jj] += bs[jj];
      }

      if constexpr (EPI == 0) { // qkv: q/k wide nt; v scalar nt scatter (transposed layout)
        const int which = c / DIM;
        const int hdc = c - which * DIM;
        const int head = hdc >> 6, d0 = hdc & 63;
        const int win = r / NW, pos = r - win * NW;
        const size_t wh = (size_t)win * HEADS + head;
        if (which == 0) {
          uint32x4 o0, o1;
          o0[0] = pack2(vv[0][0] * QSCALE, vv[0][1] * QSCALE);
          o0[1] = pack2(vv[0][2] * QSCALE, vv[0][3] * QSCALE);
          o0[2] = pack2(vv[1][0] * QSCALE, vv[1][1] * QSCALE);
          o0[3] = pack2(vv[1][2] * QSCALE, vv[1][3] * QSCALE);
          o1[0] = pack2(vv[2][0] * QSCALE, vv[2][1] * QSCALE);
          o1[1] = pack2(vv[2][2] * QSCALE, vv[2][3] * QSCALE);
          o1[2] = pack2(vv[3][0] * QSCALE, vv[3][1] * QSCALE);
          o1[3] = pack2(vv[3][2] * QSCALE, vv[3][3] * QSCALE);
          u16* dst = ep.q + (wh * NW + pos) * HD + d0;
          __builtin_nontemporal_store(o0, (uint32x4*)dst);
          __builtin_nontemporal_store(o1, (uint32x4*)(dst + 8));
        } else if (which == 1) {
          uint32x4 o0, o1;
          o0[0] = pack2(vv[0][0], vv[0][1]); o0[1] = pack2(vv[0][2], vv[0][3]);
          o0[2] = pack2(vv[1][0], vv[1][1]); o0[3] = pack2(vv[1][2], vv[1][3]);
          o1[0] = pack2(vv[2][0], vv[2][1]); o1[1] = pack2(vv[2][2], vv[2][3]);
          o1[2] = pack2(vv[3][0], vv[3][1]); o1[3] = pack2(vv[3][2], vv[3][3]);
          u16* dst = ep.k + (wh * NW + pos) * HD + d0;
          __builtin_nontemporal_store(o0, (uint32x4*)dst);
          __builtin_nontemporal_store(o1, (uint32x4*)(dst + 8));
        } else {
          #pragma unroll
          for (int jj = 0; jj < 4; ++jj)
            #pragma unroll
            for (int j2 = 0; j2 < 4; ++j2)
              __builtin_nontemporal_store(f2b(vv[jj][j2]),
                  ep.v + (wh * HD + d0 + jj * 4 + j2) * NW + pos);
        }
      } else if constexpr (EPI == 1) { // proj: window-reverse + residual -> f32 d_out
        const int win = r / NW, pos = r - win * NW;
        const int b = win >> 4, wi = win & 15;
        const int hh = (wi >> 2) * 14 + pos / 14;
        const int ww2 = (wi & 3) * 14 + pos % 14;
        const size_t orow = (size_t)b * SEQL + hh * 56 + ww2;
        const f32x4* px = (const f32x4*)(ep.x + orow * DIM + c);
        f32x4* po = (f32x4*)(ep.outf + orow * DIM + c);
        #pragma unroll
        for (int jj = 0; jj < 4; ++jj) {
          f32x4 t2 = px[jj] + vv[jj];
          __builtin_nontemporal_store(t2, po + jj);
        }
      } else if constexpr (EPI == 2) { // fc1: exact GELU -> bf16 wide nt
        float g[16];
        #pragma unroll
        for (int jj = 0; jj < 4; ++jj)
          #pragma unroll
          for (int j2 = 0; j2 < 4; ++j2) {
            float x2 = vv[jj][j2];
            g[jj * 4 + j2] = 0.5f * x2 * (1.f + erff(x2 * 0.70710678118654752f));
          }
        uint32x4 o0, o1;
        o0[0] = pack2(g[0], g[1]);   o0[1] = pack2(g[2], g[3]);
        o0[2] = pack2(g[4], g[5]);   o0[3] = pack2(g[6], g[7]);
        o1[0] = pack2(g[8], g[9]);   o1[1] = pack2(g[10], g[11]);
        o1[2] = pack2(g[12], g[13]); o1[3] = pack2(g[14], g[15]);
        u16* dst = ep.o16 + (size_t)r * N + c;
        __builtin_nontemporal_store(o0, (uint32x4*)dst);
        __builtin_nontemporal_store(o1, (uint32x4*)(dst + 8));
      } else { // fc2: residual with d_out (x1): cached read, nt write
        f32x4* po = (f32x4*)(ep.outf + (size_t)r * N + c);
        #pragma unroll
        for (int jj = 0; jj < 4; ++jj) {
          f32x4 t2 = po[jj] + vv[jj];
          __builtin_nontemporal_store(t2, po + jj);
        }
      }
    }
  }
}

// ---------------- fused window attention v3: one 4-wave block per (win*head) ------------
__global__ __launch_bounds__(256, 2)
void attn_kernel(const u16* __restrict__ qbuf, const u16* __restrict__ kbuf,
                 const u16* __restrict__ vt, const u16* __restrict__ rpb,
                 u16* __restrict__ abuf) {
  extern __shared__ __align__(16) char smem[];
  u16* sK = (u16*)smem;                  // [208][64], 16B-slot s -> s^(row&7)
  u16* sP = (u16*)(smem + 26624);        // 4 x [16][232]
  float* sT = (float*)(smem + 56320);    // 4 x [16][64]: cols 0..26 h-term, 32..58 w-term

  const int tid = threadIdx.x;
  const int l = tid & 63, w = tid >> 6;
  const int lr = l & 15, lg = l >> 4;
  const int wh = blockIdx.x;             // win*12 + head
  const int win = wh / HEADS, head = wh - win * HEADS;

  const u16* Qg = qbuf + (size_t)wh * (NW * HD);
  const u16* Kg = kbuf + (size_t)wh * (NW * HD);
  const u16* Vg = vt + (size_t)wh * (HD * NW);   // [64][196]

  for (int t = tid; t < 1664; t += 256) {
    int r8 = t >> 3, c8 = t & 7;
    int s = (t & ~7) | (c8 ^ (r8 & 7));
    if (s >= 1568) s &= 1023;
    gl_lds16(Kg + s * 8, (char*)sK + t * 16);
  }
  __syncthreads();

  f32x4 zero4 = {0.f, 0.f, 0.f, 0.f};
  u16* myP = sP + w * (16 * 232);
  float* myT = sT + w * (16 * 64);

  for (int c = 0; c < 4; ++c) {
    const int chunk = w + 4 * c;
    if (chunk > 12) break;

    int qrow = chunk * 16 + lr; if (qrow > 195) qrow = 195;
    bf16x8 aq0 = *(const bf16x8*)(Qg + (size_t)qrow * HD + lg * 8);
    bf16x8 aq1 = *(const bf16x8*)(Qg + (size_t)qrow * HD + 32 + lg * 8);

    f32x4 th[2], tw[2];
    #pragma unroll
    for (int nf2 = 0; nf2 < 2; ++nf2) {
      const u16* bh = rpb + (nf2 * 16 + lr) * 64;
      const u16* bw = rpb + 2048 + (nf2 * 16 + lr) * 64;
      f32x4 a = zero4, b = zero4;
      a = MFMA_BF16(aq0, *(const bf16x8*)(bh + lg * 8), a, 0, 0, 0);
      a = MFMA_BF16(aq1, *(const bf16x8*)(bh + 32 + lg * 8), a, 0, 0, 0);
      b = MFMA_BF16(aq0, *(const bf16x8*)(bw + lg * 8), b, 0, 0, 0);
      b = MFMA_BF16(aq1, *(const bf16x8*)(bw + 32 + lg * 8), b, 0, 0, 0);
      th[nf2] = a; tw[nf2] = b;
    }
    #pragma unroll
    for (int nf2 = 0; nf2 < 2; ++nf2)
      #pragma unroll
      for (int e = 0; e < 4; ++e) {
        myT[(lg * 4 + e) * 64 + nf2 * 16 + lr]      = th[nf2][e];
        myT[(lg * 4 + e) * 64 + 32 + nf2 * 16 + lr] = tw[nf2][e];
      }

    f32x4 accs[13];
    #pragma unroll
    for (int nf = 0; nf < 13; ++nf) {
      int krow = nf * 16 + lr;
      int ksw = (krow & 7) << 3;
      bf16x8 b0 = *(const bf16x8*)(sK + krow * 64 + ((lg * 8) ^ ksw));
      bf16x8 b1 = *(const bf16x8*)(sK + krow * 64 + ((32 + lg * 8) ^ ksw));
      f32x4 cc = zero4;
      cc = MFMA_BF16(aq0, b0, cc, 0, 0, 0);
      cc = MFMA_BF16(aq1, b1, cc, 0, 0, 0);
      accs[nf] = cc;
    }

    int ihv[4], iwv[4];
    #pragma unroll
    for (int e = 0; e < 4; ++e) {
      int gi = chunk * 16 + lg * 4 + e;
      ihv[e] = (gi * 9363) >> 17;
      iwv[e] = gi - ihv[e] * 14;
    }
    float mrow[4] = {-3e38f, -3e38f, -3e38f, -3e38f};
    #pragma unroll
    for (int nf = 0; nf < 13; ++nf) {
      int j = nf * 16 + lr;
      int jh = (j * 9363) >> 17;
      int jw = j - jh * 14;
      #pragma unroll
      for (int e = 0; e < 4; ++e) {
        int ic = lg * 4 + e;
        float s = accs[nf][e]
                + myT[ic * 64 + ((ihv[e] - jh + 13) & 63)]
                + myT[ic * 64 + 32 + (iwv[e] - jw + 13)];
        if (nf == 12 && lr >= 4) s = -1e30f;
        accs[nf][e] = s;
        mrow[e] = fmaxf(mrow[e], s);
      }
    }
    #pragma unroll
    for (int e = 0; e < 4; ++e) {
      float v = mrow[e];
      v = fmaxf(v, __shfl_xor(v, 1)); v = fmaxf(v, __shfl_xor(v, 2));
      v = fmaxf(v, __shfl_xor(v, 4)); v = fmaxf(v, __shfl_xor(v, 8));
      mrow[e] = v;
    }
    float ssum[4] = {0.f, 0.f, 0.f, 0.f};
    #pragma unroll
    for (int nf = 0; nf < 13; ++nf)
      #pragma unroll
      for (int e = 0; e < 4; ++e) {
        float p = __expf(accs[nf][e] - mrow[e]);
        accs[nf][e] = p;
        ssum[e] += p;
      }
    #pragma unroll
    for (int e = 0; e < 4; ++e) {
      float v = ssum[e];
      v += __shfl_xor(v, 1); v += __shfl_xor(v, 2);
      v += __shfl_xor(v, 4); v += __shfl_xor(v, 8);
      ssum[e] = 1.f / v;
    }
    #pragma unroll
    for (int nf = 0; nf < 13; ++nf)
      #pragma unroll
      for (int e = 0; e < 4; ++e)
        myP[(lg * 4 + e) * 232 + nf * 16 + lr] = f2b(accs[nf][e] * ssum[e]);
    #pragma unroll
    for (int e = 0; e < 4; ++e)
      myP[(lg * 4 + e) * 232 + 208 + lr] = 0;

    f32x4 acco[4];
    #pragma unroll
    for (int nf = 0; nf < 4; ++nf) acco[nf] = zero4;
    #pragma unroll
    for (int ks = 0; ks < 7; ++ks) {
      bf16x8 ap = *(const bf16x8*)(myP + lr * 232 + ks * 32 + lg * 8);
      #pragma unroll
      for (int nf = 0; nf < 4; ++nf) {
        bf16x8 bv = ldg_b8(Vg + (size_t)(nf * 16 + lr) * NW + ks * 32 + lg * 8);
        acco[nf] = MFMA_BF16(ap, bv, acco[nf], 0, 0, 0);
      }
    }
    u16* ob = abuf + (size_t)win * NW * DIM + head * HD;
    #pragma unroll
    for (int nf = 0; nf < 4; ++nf)
      #pragma unroll
      for (int e = 0; e < 4; ++e) {
        int row = chunk * 16 + lg * 4 + e;
        if (row < 196) ob[(size_t)row * DIM + nf * 16 + lr] = f2b(acco[nf][e]);
      }
  }
}

// ---------------- host launch ---------------
extern "C" void kernel_launch(void* const* d_in, const int* in_sizes, int n_in,
                              void* d_out, int out_size, void* d_ws, size_t ws_size,
                              hipStream_t stream) {
  (void)in_sizes; (void)n_in; (void)out_size; (void)ws_size;
  const float* x    = (const float*)d_in[0];
  const float* ln1s = (const float*)d_in[1];
  const float* ln1b = (const float*)d_in[2];
  const float* qkvw = (const float*)d_in[3];
  const float* qkvb = (const float*)d_in[4];
  const float* rph  = (const float*)d_in[5];
  const float* rpw  = (const float*)d_in[6];
  const float* pjw  = (const float*)d_in[7];
  const float* pjb  = (const float*)d_in[8];
  const float* ln2s = (const float*)d_in[9];
  const float* ln2b = (const float*)d_in[10];
  const float* f1w  = (const float*)d_in[11];
  const float* f1b  = (const float*)d_in[12];
  const float* f2w  = (const float*)d_in[13];
  const float* f2b_ = (const float*)d_in[14];
  float* out = (float*)d_out;

  char* ws = (char*)d_ws;
  u16* qkvwT = (u16*)ws;              // packed [2304x768]
  u16* projwT = qkvwT + 1769472;      // packed [768x768]
  u16* fc1wT  = qkvwT + 2359296;      // packed [3072x768]
  u16* fc2wT  = qkvwT + 4718592;      // packed [768x3072]
  u16* xw   = (u16*)(ws + 14155776);  // [25088][768]
  u16* qbuf = (u16*)(ws + 52690944);  // [1536][196][64]
  u16* kbuf = qbuf + 19267584;
  u16* vtb  = kbuf + 19267584;        // [1536][64][196]
  u16* h2   = (u16*)(ws + 168296448); // [25088][768]
  u16* abuf = xw;                     // alias (xw dead after qkv gemm)
  u16* h1   = xw;                     // [25088][3072] spans xw+q+k+vT regions (all dead)
  u16* rpb  = h2;                     // [2][32][64] bf16 tables; h2 written only after attn

  (void)hipFuncSetAttribute((const void*)attn_kernel,
                            hipFuncAttributeMaxDynamicSharedMemorySize, ATTN_SMEM);
  (void)hipFuncSetAttribute((const void*)gemm6_ep<768, 2304, 0>,
                            hipFuncAttributeMaxDynamicSharedMemorySize, GEMM_SMEM);
  (void)hipFuncSetAttribute((const void*)gemm6_ep<768, 768, 1>,
                            hipFuncAttributeMaxDynamicSharedMemorySize, GEMM_SMEM);
  (void)hipFuncSetAttribute((const void*)gemm6_ep<768, 3072, 2>,
                            hipFuncAttributeMaxDynamicSharedMemorySize, GEMM_SMEM);
  (void)hipFuncSetAttribute((const void*)gemm6_ep<3072, 768, 3>,
                            hipFuncAttributeMaxDynamicSharedMemorySize, GEMM_SMEM);

  pack_b<<<dim3(768 / 16, 2304 / 128), 256, 0, stream>>>(qkvw, qkvwT, 768, 2304);
  pack_b<<<dim3(768 / 16, 768 / 128),  256, 0, stream>>>(pjw, projwT, 768, 768);
  pack_b<<<dim3(768 / 16, 3072 / 128), 256, 0, stream>>>(f1w, fc1wT, 768, 3072);
  pack_b<<<dim3(3072 / 16, 768 / 128), 256, 0, stream>>>(f2w, fc2wT, 3072, 768);
  cvt_rpb<<<16, 256, 0, stream>>>(rph, rpw, rpb);

  ln_kernel<true><<<MROWS, 256, 0, stream>>>(x, ln1s, ln1b, xw);

  { Epi e{}; e.bias = qkvb; e.q = qbuf; e.k = kbuf; e.v = vtb;
    gemm6_ep<768, 2304, 0><<<196 * 18, 256, GEMM_SMEM, stream>>>(xw, qkvwT, e); }

  attn_kernel<<<1536, 256, ATTN_SMEM, stream>>>(qbuf, kbuf, vtb, rpb, abuf);

  { Epi e{}; e.bias = pjb; e.x = x; e.outf = out;
    gemm6_ep<768, 768, 1><<<196 * 6, 256, GEMM_SMEM, stream>>>(abuf, projwT, e); }

  ln_kernel<false><<<MROWS, 256, 0, stream>>>(out, ln2s, ln2b, h2);

  { Epi e{}; e.bias = f1b; e.o16 = h1;
    gemm6_ep<768, 3072, 2><<<196 * 24, 256, GEMM_SMEM, stream>>>(h2, fc1wT, e); }

  { Epi e{}; e.bias = f2b_; e.outf = out;
    gemm6_ep<3072, 768, 3><<<196 * 6, 256, GEMM_SMEM, stream>>>(h1, fc2wT, e); }
}